// Round 3
// baseline (329.754 us; speedup 1.0000x reference)
//
#include <hip/hip_runtime.h>
#include <hip/hip_bf16.h>

#define NN 2048
#define FF 64
#define NH 8
#define BDIM 4
#define BH 32        // BDIM*NH
#define NB 256       // value bins per (b,head)
#define NCH 64       // scan chunks per (b,head)
#define CSZ 32       // elements per scan chunk (NCH*CSZ == NN)

__device__ __forceinline__ float LDIN(const void* p, size_t i, int b16) {
    return b16 ? __bfloat162float(((const __hip_bfloat16*)p)[i]) : ((const float*)p)[i];
}
__device__ __forceinline__ unsigned encf(float x) {
    unsigned u = __float_as_uint(x);
    return (u & 0x80000000u) ? ~u : (u | 0x80000000u);
}
__device__ __forceinline__ float decf(unsigned k) {
    unsigned u = (k & 0x80000000u) ? (k & 0x7FFFFFFFu) : ~k;
    return __uint_as_float(u);
}
__device__ __forceinline__ int binOf(float d, float dmin, float inv) {
    int b = (int)((d - dmin) * inv);
    return b < 0 ? 0 : (b > NB - 1 ? NB - 1 : b);
}

// ---- Kernel 0: dtype sniff + init min/max slots ------------------------------
__global__ void k_init(const void* __restrict__ h, int* __restrict__ flag,
                       unsigned* __restrict__ mm) {
    int l = threadIdx.x;
    unsigned word = ((const unsigned*)h)[l];
    unsigned lowexp = (word >> 7) & 0xFFu;
    bool plaus = (lowexp >= 96u && lowexp <= 159u);
    unsigned long long m = __ballot(plaus);
    if (l == 0) flag[0] = (__popcll(m) >= 48) ? 1 : 0;
    mm[l] = (l & 1) ? 0u : 0xFFFFFFFFu;   // [2bh]=min slot, [2bh+1]=max slot
}

// ---- Kernel 1: h_prime = h@w (fp32), s/d + per-(b,h) d min/max ---------------
__global__ __launch_bounds__(512) void k_proj(
    const void* __restrict__ h, const void* __restrict__ w,
    const void* __restrict__ asrc, const void* __restrict__ adst,
    const int* __restrict__ flag,
    float* __restrict__ hp, float* __restrict__ sArr, float* __restrict__ dArr,
    unsigned* __restrict__ mm)
{
    const int b16 = flag[0];
    const int tid = threadIdx.x;
    const int hd = tid >> 6;
    const int o  = tid & 63;
    const int r0 = blockIdx.x * 8;

    __shared__ float hrow[8][FF];
    hrow[tid >> 6][tid & 63] = LDIN(h, (size_t)(r0 + (tid >> 6)) * FF + (tid & 63), b16);
    __syncthreads();

    float acc[8];
#pragma unroll
    for (int r = 0; r < 8; ++r) acc[r] = 0.f;

    const size_t wbase = (size_t)hd * FF * FF + o;
#pragma unroll 8
    for (int f = 0; f < FF; ++f) {
        float wv = LDIN(w, wbase + (size_t)f * FF, b16);
#pragma unroll
        for (int r = 0; r < 8; ++r) acc[r] += hrow[r][f] * wv;
    }

    const float av = LDIN(asrc, hd * FF + o, b16);
    const float bv = LDIN(adst, hd * FF + o, b16);
    const int b  = r0 >> 11;
    const int bh = b * NH + hd;

    float wmin = 3.4e38f, wmax = -3.4e38f;
#pragma unroll
    for (int r = 0; r < 8; ++r) {
        int i = (r0 + r) & (NN - 1);
        hp[((size_t)bh * NN + i) * FF + o] = acc[r];
        float t  = tanhf(acc[r]);
        float sv = t * av;
        float dv = t * bv;
#pragma unroll
        for (int off = 32; off >= 1; off >>= 1) {
            sv += __shfl_xor(sv, off, 64);
            dv += __shfl_xor(dv, off, 64);
        }
        wmin = fminf(wmin, dv);
        wmax = fmaxf(wmax, dv);
        if (o == 0) { sArr[bh * NN + i] = sv; dArr[bh * NN + i] = dv; }
    }
    if (o == 0) {
        atomicMin(&mm[2 * bh],     encf(wmin));
        atomicMax(&mm[2 * bh + 1], encf(wmax));
    }
}

// ---- Kernel 2: counting sort by value bins (exact order via per-bin sort) ----
__global__ __launch_bounds__(256) void k_count(
    const float* __restrict__ dArr, const unsigned* __restrict__ mm,
    float* __restrict__ sd, int* __restrict__ sj, int* __restrict__ binSt)
{
    __shared__ float ld[NN];
    __shared__ float s2[NN];
    __shared__ int   j2[NN];
    __shared__ int   hist[NB];
    __shared__ int   hoff[NB + 1];
    __shared__ int   cur[NB];

    const int bh = blockIdx.x, t = threadIdx.x;
    const float dmin = decf(mm[2 * bh]);
    const float dmax = decf(mm[2 * bh + 1]);
    const float inv  = (dmax > dmin) ? (float)NB / (dmax - dmin) : 0.f;

    for (int e = t; e < NN; e += 256) ld[e] = dArr[bh * NN + e];
    for (int b = t; b < NB; b += 256) hist[b] = 0;
    __syncthreads();
    for (int e = t; e < NN; e += 256) atomicAdd(&hist[binOf(ld[e], dmin, inv)], 1);
    __syncthreads();
    if (t == 0) {
        int run = 0;
        for (int b = 0; b < NB; ++b) { hoff[b] = run; run += hist[b]; }
        hoff[NB] = run;
    }
    __syncthreads();
    for (int b = t; b < NB; b += 256) cur[b] = hoff[b];
    __syncthreads();
    for (int e = t; e < NN; e += 256) {
        int b = binOf(ld[e], dmin, inv);
        int p = atomicAdd(&cur[b], 1);
        s2[p] = ld[e]; j2[p] = e;
    }
    __syncthreads();
    if (t < NB) {                      // per-bin insertion sort (~8 elems avg)
        int st = hoff[t], en = hoff[t + 1];
        for (int a = st + 1; a < en; ++a) {
            float kv = s2[a]; int ji = j2[a]; int b = a - 1;
            while (b >= st && s2[b] > kv) { s2[b + 1] = s2[b]; j2[b + 1] = j2[b]; --b; }
            s2[b + 1] = kv; j2[b + 1] = ji;
        }
    }
    __syncthreads();
    for (int e = t; e < NN; e += 256) { sd[bh * NN + e] = s2[e]; sj[bh * NN + e] = j2[e]; }
    for (int b = t; b < NB + 1; b += 256) binSt[bh * (NB + 1) + b] = hoff[b];
}

// ---- Kernel 3: per-chunk sums (chunk = 32 sorted elements) -------------------
__global__ __launch_bounds__(64) void k_chunk(
    const float* __restrict__ sd, const int* __restrict__ sj,
    const float* __restrict__ hp,
    float* __restrict__ cH, float* __restrict__ cL,
    float* __restrict__ cHs, float* __restrict__ cLs)
{
    const int bh = blockIdx.x >> 6, c = blockIdx.x & 63;
    const int o  = threadIdx.x;
    float aH = 0.f, aL = 0.f, sH = 0.f, sL = 0.f;
#pragma unroll 4
    for (int m0 = 0; m0 < CSZ; ++m0) {
        const int m = c * CSZ + m0;
        float dv = sd[bh * NN + m];
        int   j  = sj[bh * NN + m];
        float v  = hp[((size_t)bh * NN + j) * FF + o];
        float e1 = __expf(dv), e2 = __expf(0.2f * dv);
        aH += e1 * v; aL += e2 * v; sH += e1; sL += e2;
    }
    cH[((size_t)bh * NCH + c) * FF + o] = aH;
    cL[((size_t)bh * NCH + c) * FF + o] = aL;
    if (o == 0) { cHs[bh * NCH + c] = sH; cLs[bh * NCH + c] = sL; }
}

// ---- Kernel 4: offsets + element-granular SH/SL emission ---------------------
__global__ __launch_bounds__(64) void k_scan2(
    const float* __restrict__ sd, const int* __restrict__ sj,
    const float* __restrict__ hp,
    const float* __restrict__ cH, const float* __restrict__ cL,
    const float* __restrict__ cHs, const float* __restrict__ cLs,
    float* __restrict__ SH, float* __restrict__ SL,
    float* __restrict__ shs, float* __restrict__ sls)
{
    const int bh = blockIdx.x >> 6, c = blockIdx.x & 63;
    const int o  = threadIdx.x;

    float offH = 0.f, offHs = 0.f, offL = 0.f, offLs = 0.f;
    for (int cc = c + 1; cc < NCH; ++cc) {
        offH  += cH[((size_t)bh * NCH + cc) * FF + o];
        offHs += cHs[bh * NCH + cc];
    }
    for (int cc = 0; cc < c; ++cc) {
        offL  += cL[((size_t)bh * NCH + cc) * FF + o];
        offLs += cLs[bh * NCH + cc];
    }

    float runH = offH, runHs = offHs;
    for (int m0 = CSZ - 1; m0 >= 0; --m0) {
        const int m = c * CSZ + m0;
        float dv = sd[bh * NN + m];
        int   j  = sj[bh * NN + m];
        float v  = hp[((size_t)bh * NN + j) * FF + o];
        float e1 = __expf(dv);
        runH += e1 * v; runHs += e1;
        SH[((size_t)bh * (NN + 1) + m) * FF + o] = runH;
        if (o == 0) shs[bh * (NN + 1) + m] = runHs;
    }
    float runL = offL, runLs = offLs;
    for (int m0 = 0; m0 < CSZ; ++m0) {
        const int m = c * CSZ + m0;
        SL[((size_t)bh * (NN + 1) + m) * FF + o] = runL;
        if (o == 0) sls[bh * (NN + 1) + m] = runLs;
        float dv = sd[bh * NN + m];
        int   j  = sj[bh * NN + m];
        float v  = hp[((size_t)bh * NN + j) * FF + o];
        float e2 = __expf(0.2f * dv);
        runL += e2 * v; runLs += e2;
    }
    if (c == NCH - 1) {
        SH[((size_t)bh * (NN + 1) + NN) * FF + o] = 0.f;
        SL[((size_t)bh * (NN + 1) + NN) * FF + o] = runL;
        if (o == 0) { shs[bh * (NN + 1) + NN] = 0.f; sls[bh * (NN + 1) + NN] = runLs; }
    }
}

// ---- Kernel 5: per-row bin lookup + ballot rank + combine --------------------
__global__ __launch_bounds__(256) void k_out(
    const float* __restrict__ sArr, const float* __restrict__ sd,
    const int* __restrict__ binSt, const unsigned* __restrict__ mm,
    const float* __restrict__ SH, const float* __restrict__ SL,
    const float* __restrict__ shs, const float* __restrict__ sls,
    const void* __restrict__ bias, const int* __restrict__ flag, void* __restrict__ out)
{
    const int b16 = flag[0];
    const int bh = blockIdx.x >> 8;
    const int i0 = (blockIdx.x & 255) * 8;
    const int wv = threadIdx.x >> 6;
    const int o  = threadIdx.x & 63;

    const float dmin = decf(mm[2 * bh]);
    const float dmax = decf(mm[2 * bh + 1]);
    const float inv  = (dmax > dmin) ? (float)NB / (dmax - dmin) : 0.f;
    const float biasv = LDIN(bias, o, b16);

    for (int rr = 0; rr < 2; ++rr) {
        const int i = i0 + wv * 2 + rr;
        const float sv  = sArr[bh * NN + i];
        const float tau = -sv;
        const int b  = binOf(tau, dmin, inv);
        const int st = binSt[bh * (NB + 1) + b];
        const int en = binSt[bh * (NB + 1) + b + 1];
        int cnt = 0;
        for (int base = st; base < en; base += 64) {
            int idx = base + o;
            bool p = (idx < en) && (sd[bh * NN + idx] < tau);
            cnt += __popcll(__ballot(p));
        }
        const int k = st + cnt;                       // first index with sd >= tau
        const size_t kk = (size_t)bh * (NN + 1) + k;
        const float es  = __expf(sv);
        const float es2 = __expf(0.2f * sv);
        const float num = es * SH[kk * FF + o] + es2 * SL[kk * FF + o];
        const float den = es * shs[kk] + es2 * sls[kk];
        const float res = num / den + biasv;
        const size_t oi = ((size_t)bh * NN + i) * FF + o;
        if (b16) ((__hip_bfloat16*)out)[oi] = __float2bfloat16(res);
        else     ((float*)out)[oi] = res;
    }
}

extern "C" void kernel_launch(void* const* d_in, const int* in_sizes, int n_in,
                              void* d_out, int out_size, void* d_ws, size_t ws_size,
                              hipStream_t stream) {
    const void* h    = d_in[0];
    // d_in[1] = adj (bool) — unused by reference
    const void* w    = d_in[2];
    const void* asrc = d_in[3];
    const void* adst = d_in[4];
    const void* bias = d_in[5];

    float* ws = (float*)d_ws;
    int*      flag  = (int*)ws;                           // 4
    unsigned* mm    = (unsigned*)(flag + 4);              // BH*2 = 64
    float* hp    = (float*)(mm + 64);                     // BH*NN*FF
    float* sArr  = hp + (size_t)BH * NN * FF;             // BH*NN
    float* dArr  = sArr + BH * NN;
    float* sd    = dArr + BH * NN;
    int*   sj    = (int*)(sd + BH * NN);
    int*   binSt = sj + BH * NN;                          // BH*(NB+1)
    float* cH    = (float*)(binSt + BH * (NB + 1));       // BH*NCH*FF
    float* cL    = cH + (size_t)BH * NCH * FF;
    float* cHs   = cL + (size_t)BH * NCH * FF;            // BH*NCH
    float* cLs   = cHs + BH * NCH;
    float* SH    = cLs + BH * NCH;                        // BH*(NN+1)*FF
    float* SL    = SH + (size_t)BH * (NN + 1) * FF;
    float* shs   = SL + (size_t)BH * (NN + 1) * FF;       // BH*(NN+1)
    float* sls   = shs + BH * (NN + 1);

    k_init<<<1, 64, 0, stream>>>(h, flag, mm);
    k_proj<<<(BDIM * NN) / 8, 512, 0, stream>>>(h, w, asrc, adst, flag, hp, sArr, dArr, mm);
    k_count<<<BH, 256, 0, stream>>>(dArr, mm, sd, sj, binSt);
    k_chunk<<<BH * NCH, 64, 0, stream>>>(sd, sj, hp, cH, cL, cHs, cLs);
    k_scan2<<<BH * NCH, 64, 0, stream>>>(sd, sj, hp, cH, cL, cHs, cLs, SH, SL, shs, sls);
    k_out<<<BH * 256, 256, 0, stream>>>(sArr, sd, binSt, mm, SH, SL, shs, sls, bias, flag, d_out);
}

// Round 4
// 280.844 us; speedup vs baseline: 1.1742x; 1.1742x over previous
//
#include <hip/hip_runtime.h>
#include <hip/hip_bf16.h>

#define NN 2048
#define FF 64
#define NH 8
#define BDIM 4
#define BH 32        // BDIM*NH
#define NB 512       // value bins per (b,head)

typedef __attribute__((ext_vector_type(8))) short short8;
typedef __attribute__((ext_vector_type(4))) float floatx4;

__device__ __forceinline__ float LDIN(const void* p, size_t i, int b16) {
    return b16 ? __bfloat162float(((const __hip_bfloat16*)p)[i]) : ((const float*)p)[i];
}
__device__ __forceinline__ unsigned encf(float x) {
    unsigned u = __float_as_uint(x);
    return (u & 0x80000000u) ? ~u : (u | 0x80000000u);
}
__device__ __forceinline__ float decf(unsigned k) {
    unsigned u = (k & 0x80000000u) ? (k & 0x7FFFFFFFu) : ~k;
    return __uint_as_float(u);
}
__device__ __forceinline__ int binOf(float d, float dmin, float inv) {
    int b = (int)((d - dmin) * inv);
    return b < 0 ? 0 : (b > NB - 1 ? NB - 1 : b);
}
__device__ __forceinline__ void split2(float x, ushort& hi, ushort& lo) {
    unsigned u = __float_as_uint(x);
    hi = (ushort)(u >> 16);
    float fl = x - __uint_as_float(u & 0xFFFF0000u);
    lo = (ushort)(__float_as_uint(fl) >> 16);
}

// ---- Kernel 0: dtype sniff + init min/max slots ------------------------------
__global__ void k_init(const void* __restrict__ h, int* __restrict__ flag,
                       unsigned* __restrict__ mm) {
    int l = threadIdx.x;
    unsigned word = ((const unsigned*)h)[l];
    unsigned lowexp = (word >> 7) & 0xFFu;
    bool plaus = (lowexp >= 96u && lowexp <= 159u);
    unsigned long long m = __ballot(plaus);
    if (l == 0) flag[0] = (__popcll(m) >= 48) ? 1 : 0;
    mm[l] = (l & 1) ? 0u : 0xFFFFFFFFu;   // [2bh]=min slot, [2bh+1]=max slot
}

// ---- Kernel 1: split-bf16 MFMA GEMM: hp = h@w (fp32-grade), s/d, d min/max ---
// block = (batch b, head hd, 128-row tile). 256 thr = 4 waves, 2 M-tiles/wave.
__global__ __launch_bounds__(256) void k_proj(
    const void* __restrict__ h, const void* __restrict__ w,
    const void* __restrict__ asrc, const void* __restrict__ adst,
    const int* __restrict__ flag,
    float* __restrict__ hp, float* __restrict__ sArr, float* __restrict__ dArr,
    unsigned* __restrict__ mm)
{
    const int b16 = flag[0];
    const int t  = threadIdx.x;
    const int rt = blockIdx.x & 15;
    const int hd = (blockIdx.x >> 4) & 7;
    const int b  = blockIdx.x >> 7;
    const int bh = b * NH + hd;
    const int r0 = rt * 128;

    __shared__ ushort aHi[128 * 72];   // row stride 72 shorts = 144 B (16B-aligned, bank-safe)
    __shared__ ushort aLo[128 * 72];
    __shared__ ushort bHi[64 * 72];    // transposed w: bHi[n][k]
    __shared__ ushort bLo[64 * 72];

    const size_t hbase = ((size_t)b * NN + r0) * FF;
    for (int e = t; e < 128 * 64; e += 256) {
        float x = LDIN(h, hbase + e, b16);
        ushort hi, lo; split2(x, hi, lo);
        int r = e >> 6, f = e & 63;
        aHi[r * 72 + f] = hi; aLo[r * 72 + f] = lo;
    }
    const size_t wb = (size_t)hd * FF * FF;
    for (int e = t; e < 64 * 64; e += 256) {
        int k = e >> 6, n = e & 63;
        float x = LDIN(w, wb + e, b16);     // coalesced in (k,n)
        ushort hi, lo; split2(x, hi, lo);
        bHi[n * 72 + k] = hi; bLo[n * 72 + k] = lo;
    }
    __syncthreads();

    const int wv = t >> 6, lane = t & 63;
    const int ml = lane & 15, q = lane >> 4;

    short8 bhf[4][2], blf[4][2];
#pragma unroll
    for (int nt = 0; nt < 4; ++nt)
#pragma unroll
        for (int kc = 0; kc < 2; ++kc) {
            int n = nt * 16 + ml, k = kc * 32 + q * 8;
            bhf[nt][kc] = *(const short8*)&bHi[n * 72 + k];
            blf[nt][kc] = *(const short8*)&bLo[n * 72 + k];
        }
    float aS[4], aD[4];
#pragma unroll
    for (int nt = 0; nt < 4; ++nt) {
        aS[nt] = LDIN(asrc, hd * FF + nt * 16 + ml, b16);
        aD[nt] = LDIN(adst, hd * FF + nt * 16 + ml, b16);
    }

    float wmin = 3.4e38f, wmax = -3.4e38f;
    for (int mt = wv; mt < 8; mt += 4) {
        const int rb = mt * 16;
        short8 ah[2], al[2];
#pragma unroll
        for (int kc = 0; kc < 2; ++kc) {
            int k = kc * 32 + q * 8;
            ah[kc] = *(const short8*)&aHi[(rb + ml) * 72 + k];
            al[kc] = *(const short8*)&aLo[(rb + ml) * 72 + k];
        }
        floatx4 acc[4];
#pragma unroll
        for (int nt = 0; nt < 4; ++nt) {
            floatx4 a = {0.f, 0.f, 0.f, 0.f};
#pragma unroll
            for (int kc = 0; kc < 2; ++kc) {
                a = __builtin_amdgcn_mfma_f32_16x16x32_bf16(ah[kc], bhf[nt][kc], a, 0, 0, 0);
                a = __builtin_amdgcn_mfma_f32_16x16x32_bf16(ah[kc], blf[nt][kc], a, 0, 0, 0);
                a = __builtin_amdgcn_mfma_f32_16x16x32_bf16(al[kc], bhf[nt][kc], a, 0, 0, 0);
            }
            acc[nt] = a;
        }
        float ps[4] = {0.f, 0.f, 0.f, 0.f}, pd[4] = {0.f, 0.f, 0.f, 0.f};
#pragma unroll
        for (int nt = 0; nt < 4; ++nt)
#pragma unroll
            for (int reg = 0; reg < 4; ++reg) {
                int row = q * 4 + reg;               // C/D: col=lane&15, row=quad*4+reg
                int i = r0 + rb + row;
                float v = acc[nt][reg];
                hp[((size_t)bh * NN + i) * FF + nt * 16 + ml] = v;
                float tv = tanhf(v);
                ps[reg] += tv * aS[nt];
                pd[reg] += tv * aD[nt];
            }
#pragma unroll
        for (int msk = 1; msk < 16; msk <<= 1)
#pragma unroll
            for (int reg = 0; reg < 4; ++reg) {
                ps[reg] += __shfl_xor(ps[reg], msk, 64);
                pd[reg] += __shfl_xor(pd[reg], msk, 64);
            }
        if (ml == 0) {
#pragma unroll
            for (int reg = 0; reg < 4; ++reg) {
                int i = r0 + rb + q * 4 + reg;
                sArr[bh * NN + i] = ps[reg];
                dArr[bh * NN + i] = pd[reg];
                wmin = fminf(wmin, pd[reg]);
                wmax = fmaxf(wmax, pd[reg]);
            }
        }
    }
#pragma unroll
    for (int msk = 1; msk < 64; msk <<= 1) {
        wmin = fminf(wmin, __shfl_xor(wmin, msk, 64));
        wmax = fmaxf(wmax, __shfl_xor(wmax, msk, 64));
    }
    if (lane == 0) {
        atomicMin(&mm[2 * bh],     encf(wmin));
        atomicMax(&mm[2 * bh + 1], encf(wmax));
    }
}

// ---- Kernel 2: bin d into NB value-bins (no within-bin ordering needed) ------
__global__ __launch_bounds__(256) void k_bin(
    const float* __restrict__ dArr, const unsigned* __restrict__ mm,
    float* __restrict__ bd, int* __restrict__ bj, int* __restrict__ binSt,
    float* __restrict__ shsb, float* __restrict__ slsb)
{
    __shared__ float ld[NN];
    __shared__ float s2[NN];
    __shared__ int   j2[NN];
    __shared__ int   hist[NB];
    __shared__ int   hoff[NB + 1];
    __shared__ int   cur[NB];
    __shared__ float sh1[NB];
    __shared__ float sl1[NB];

    const int bh = blockIdx.x, t = threadIdx.x;
    const float dmin = decf(mm[2 * bh]);
    const float dmax = decf(mm[2 * bh + 1]);
    const float inv  = (dmax > dmin) ? (float)NB / (dmax - dmin) : 0.f;

    for (int e = t; e < NN; e += 256) ld[e] = dArr[bh * NN + e];
    for (int bb = t; bb < NB; bb += 256) hist[bb] = 0;
    __syncthreads();
    for (int e = t; e < NN; e += 256) atomicAdd(&hist[binOf(ld[e], dmin, inv)], 1);
    __syncthreads();
    if (t == 0) {
        int run = 0;
        for (int bb = 0; bb < NB; ++bb) { hoff[bb] = run; run += hist[bb]; }
        hoff[NB] = run;
    }
    __syncthreads();
    for (int bb = t; bb < NB; bb += 256) cur[bb] = hoff[bb];
    __syncthreads();
    for (int e = t; e < NN; e += 256) {
        int bb = binOf(ld[e], dmin, inv);
        int p = atomicAdd(&cur[bb], 1);
        s2[p] = ld[e]; j2[p] = e;
    }
    __syncthreads();
    for (int bb = t; bb < NB; bb += 256) {       // per-bin scalar exp sums
        float sH = 0.f, sL = 0.f;
        for (int m = hoff[bb]; m < hoff[bb + 1]; ++m) {
            float dv = s2[m];
            sH += __expf(dv); sL += __expf(0.2f * dv);
        }
        sh1[bb] = sH; sl1[bb] = sL;
    }
    __syncthreads();
    for (int e = t; e < NN; e += 256) { bd[bh * NN + e] = s2[e]; bj[bh * NN + e] = j2[e]; }
    for (int bb = t; bb < NB + 1; bb += 256) binSt[bh * (NB + 1) + bb] = hoff[bb];
    if (t == 0) {
        float run = 0.f;
        shsb[bh * (NB + 1) + NB] = 0.f;
        for (int bb = NB - 1; bb >= 0; --bb) { run += sh1[bb]; shsb[bh * (NB + 1) + bb] = run; }
        run = 0.f;
        for (int bb = 0; bb < NB; ++bb) { slsb[bh * (NB + 1) + bb] = run; run += sl1[bb]; }
        slsb[bh * (NB + 1) + NB] = run;
    }
}

// ---- Kernel 3: per-bin weighted vector sums (1 block per bin) ----------------
__global__ __launch_bounds__(64) void k_binsum(
    const float* __restrict__ bd, const int* __restrict__ bj,
    const int* __restrict__ binSt, const float* __restrict__ hp,
    float* __restrict__ bHv, float* __restrict__ bLv)
{
    const int bh = blockIdx.x >> 9;
    const int bb = blockIdx.x & (NB - 1);
    const int o  = threadIdx.x;
    const int st = binSt[bh * (NB + 1) + bb], en = binSt[bh * (NB + 1) + bb + 1];
    float aH = 0.f, aL = 0.f;
    for (int m = st; m < en; ++m) {
        float dv = bd[bh * NN + m];
        int   j  = bj[bh * NN + m];
        float v  = hp[((size_t)bh * NN + j) * FF + o];
        aH += __expf(dv) * v;
        aL += __expf(0.2f * dv) * v;
    }
    bHv[((size_t)bh * NB + bb) * FF + o] = aH;
    bLv[((size_t)bh * NB + bb) * FF + o] = aL;
}

// ---- Kernel 4: bin-granular suffix (H) / exclusive-prefix (L) vector scans ---
__global__ __launch_bounds__(128) void k_scanC(
    const float* __restrict__ bHv, const float* __restrict__ bLv,
    float* __restrict__ SHb, float* __restrict__ SLb)
{
    const int bh = blockIdx.x;
    const int wv = threadIdx.x >> 6, o = threadIdx.x & 63;
    if (wv == 0) {
        float run = 0.f;
        SHb[((size_t)bh * (NB + 1) + NB) * FF + o] = 0.f;
#pragma unroll 4
        for (int bb = NB - 1; bb >= 0; --bb) {
            run += bHv[((size_t)bh * NB + bb) * FF + o];
            SHb[((size_t)bh * (NB + 1) + bb) * FF + o] = run;
        }
    } else {
        float run = 0.f;
#pragma unroll 4
        for (int bb = 0; bb < NB; ++bb) {
            SLb[((size_t)bh * (NB + 1) + bb) * FF + o] = run;
            run += bLv[((size_t)bh * NB + bb) * FF + o];
        }
        SLb[((size_t)bh * (NB + 1) + NB) * FF + o] = run;
    }
}

// ---- Kernel 5: per-row bin lookup + tiny partial bin + combine ---------------
__global__ __launch_bounds__(256) void k_out(
    const float* __restrict__ sArr, const float* __restrict__ bd,
    const int* __restrict__ bj, const int* __restrict__ binSt,
    const unsigned* __restrict__ mm, const float* __restrict__ hp,
    const float* __restrict__ SHb, const float* __restrict__ SLb,
    const float* __restrict__ shsb, const float* __restrict__ slsb,
    const void* __restrict__ bias, const int* __restrict__ flag, void* __restrict__ out)
{
    const int b16 = flag[0];
    const int bh = blockIdx.x >> 7;
    const int i0 = (blockIdx.x & 127) * 16;
    const int wv = threadIdx.x >> 6, o = threadIdx.x & 63;
    const float dmin = decf(mm[2 * bh]);
    const float dmax = decf(mm[2 * bh + 1]);
    const float inv  = (dmax > dmin) ? (float)NB / (dmax - dmin) : 0.f;
    const float biasv = LDIN(bias, o, b16);

    for (int rr = 0; rr < 4; ++rr) {
        const int i = i0 + wv * 4 + rr;
        const float sv  = sArr[bh * NN + i];
        const float tau = -sv;
        const int bb = binOf(tau, dmin, inv);
        const int st = binSt[bh * (NB + 1) + bb], en = binSt[bh * (NB + 1) + bb + 1];
        float pH = 0.f, pL = 0.f, psH = 0.f, psL = 0.f;
        for (int m = st; m < en; ++m) {           // avg ~4 elements; wave-uniform branch
            float dv = bd[bh * NN + m];
            int   j  = bj[bh * NN + m];
            float v  = hp[((size_t)bh * NN + j) * FF + o];
            if (dv >= tau) { float e1 = __expf(dv);        pH += e1 * v; psH += e1; }
            else           { float e2 = __expf(0.2f * dv); pL += e2 * v; psL += e2; }
        }
        const size_t ib = (size_t)bh * (NB + 1);
        const float es  = __expf(sv);
        const float es2 = __expf(0.2f * sv);
        const float num = es * (SHb[(ib + bb + 1) * FF + o] + pH)
                        + es2 * (SLb[(ib + bb) * FF + o] + pL);
        const float den = es * (shsb[ib + bb + 1] + psH) + es2 * (slsb[ib + bb] + psL);
        const float res = num / den + biasv;
        const size_t oi = ((size_t)bh * NN + i) * FF + o;
        if (b16) ((__hip_bfloat16*)out)[oi] = __float2bfloat16(res);
        else     ((float*)out)[oi] = res;
    }
}

extern "C" void kernel_launch(void* const* d_in, const int* in_sizes, int n_in,
                              void* d_out, int out_size, void* d_ws, size_t ws_size,
                              hipStream_t stream) {
    const void* h    = d_in[0];
    // d_in[1] = adj (bool) — unused by reference
    const void* w    = d_in[2];
    const void* asrc = d_in[3];
    const void* adst = d_in[4];
    const void* bias = d_in[5];

    float* ws = (float*)d_ws;
    int*      flag = (int*)ws;                          // 4
    unsigned* mm   = (unsigned*)(flag + 4);             // 64
    float* hp    = (float*)(mm + 64);                   // BH*NN*FF
    float* sArr  = hp + (size_t)BH * NN * FF;           // BH*NN
    float* dArr  = sArr + BH * NN;
    float* bd    = dArr + BH * NN;
    int*   bj    = (int*)(bd + BH * NN);
    int*   binSt = bj + BH * NN;                        // BH*(NB+1)
    float* shsb  = (float*)(binSt + BH * (NB + 1));     // BH*(NB+1)
    float* slsb  = shsb + BH * (NB + 1);
    float* bHv   = slsb + BH * (NB + 1);                // BH*NB*FF
    float* bLv   = bHv + (size_t)BH * NB * FF;
    float* SHb   = bLv + (size_t)BH * NB * FF;          // BH*(NB+1)*FF
    float* SLb   = SHb + (size_t)BH * (NB + 1) * FF;

    k_init<<<1, 64, 0, stream>>>(h, flag, mm);
    k_proj<<<512, 256, 0, stream>>>(h, w, asrc, adst, flag, hp, sArr, dArr, mm);
    k_bin<<<BH, 256, 0, stream>>>(dArr, mm, bd, bj, binSt, shsb, slsb);
    k_binsum<<<BH * NB, 64, 0, stream>>>(bd, bj, binSt, hp, bHv, bLv);
    k_scanC<<<BH, 128, 0, stream>>>(bHv, bLv, SHb, SLb);
    k_out<<<BH * 128, 256, 0, stream>>>(sArr, bd, bj, binSt, mm, hp,
                                        SHb, SLb, shsb, slsb, bias, flag, d_out);
}

// Round 5
// 219.831 us; speedup vs baseline: 1.5000x; 1.2775x over previous
//
#include <hip/hip_runtime.h>
#include <hip/hip_bf16.h>

#define NN 2048
#define FF 64
#define NH 8
#define BDIM 4
#define BH 32        // BDIM*NH
#define NB 512       // value bins per (b,head)
#define NCH2 32      // cut-chunks per (b,head)
#define CL 64        // elements per cut-chunk (NCH2*CL == NN)

typedef __attribute__((ext_vector_type(8))) short short8;
typedef __attribute__((ext_vector_type(4))) float floatx4;

__device__ __forceinline__ float LDIN(const void* p, size_t i, int b16) {
    return b16 ? __bfloat162float(((const __hip_bfloat16*)p)[i]) : ((const float*)p)[i];
}
__device__ __forceinline__ unsigned encf(float x) {
    unsigned u = __float_as_uint(x);
    return (u & 0x80000000u) ? ~u : (u | 0x80000000u);
}
__device__ __forceinline__ float decf(unsigned k) {
    unsigned u = (k & 0x80000000u) ? (k & 0x7FFFFFFFu) : ~k;
    return __uint_as_float(u);
}
__device__ __forceinline__ int binOf(float d, float dmin, float inv) {
    int b = (int)((d - dmin) * inv);
    return b < 0 ? 0 : (b > NB - 1 ? NB - 1 : b);
}
__device__ __forceinline__ void split2(float x, ushort& hi, ushort& lo) {
    unsigned u = __float_as_uint(x);
    hi = (ushort)(u >> 16);
    float fl = x - __uint_as_float(u & 0xFFFF0000u);
    lo = (ushort)(__float_as_uint(fl) >> 16);
}
__device__ __forceinline__ int wave_iscan(int v) {
    const int lane = threadIdx.x & 63;
#pragma unroll
    for (int off = 1; off < 64; off <<= 1) {
        int u = __shfl_up(v, off, 64);
        if (lane >= off) v += u;
    }
    return v;
}
__device__ __forceinline__ float wave_fscan(float v) {
    const int lane = threadIdx.x & 63;
#pragma unroll
    for (int off = 1; off < 64; off <<= 1) {
        float u = __shfl_up(v, off, 64);
        if (lane >= off) v += u;
    }
    return v;
}

// ---- Kernel 0: dtype sniff + init min/max slots ------------------------------
__global__ void k_init(const void* __restrict__ h, int* __restrict__ flag,
                       unsigned* __restrict__ mm) {
    int l = threadIdx.x;
    unsigned word = ((const unsigned*)h)[l];
    unsigned lowexp = (word >> 7) & 0xFFu;
    bool plaus = (lowexp >= 96u && lowexp <= 159u);
    unsigned long long m = __ballot(plaus);
    if (l == 0) flag[0] = (__popcll(m) >= 48) ? 1 : 0;
    mm[l] = (l & 1) ? 0u : 0xFFFFFFFFu;   // [2bh]=min slot, [2bh+1]=max slot
}

// ---- Kernel 1: split-bf16 MFMA GEMM: hp = h@w (bf16 store), s/d, d min/max ---
__global__ __launch_bounds__(256) void k_proj(
    const void* __restrict__ h, const void* __restrict__ w,
    const void* __restrict__ asrc, const void* __restrict__ adst,
    const int* __restrict__ flag,
    __hip_bfloat16* __restrict__ hpB, float* __restrict__ sArr, float* __restrict__ dArr,
    unsigned* __restrict__ mm)
{
    const int b16 = flag[0];
    const int t  = threadIdx.x;
    const int rt = blockIdx.x & 15;
    const int hd = (blockIdx.x >> 4) & 7;
    const int b  = blockIdx.x >> 7;
    const int bh = b * NH + hd;
    const int r0 = rt * 128;

    __shared__ ushort aHi[128 * 72];
    __shared__ ushort aLo[128 * 72];
    __shared__ ushort bHi[64 * 72];    // transposed w: bHi[n][k]
    __shared__ ushort bLo[64 * 72];

    const size_t hbase = ((size_t)b * NN + r0) * FF;
    for (int e = t; e < 128 * 64; e += 256) {
        float x = LDIN(h, hbase + e, b16);
        ushort hi, lo; split2(x, hi, lo);
        int r = e >> 6, f = e & 63;
        aHi[r * 72 + f] = hi; aLo[r * 72 + f] = lo;
    }
    const size_t wb = (size_t)hd * FF * FF;
    for (int e = t; e < 64 * 64; e += 256) {
        int k = e >> 6, n = e & 63;
        float x = LDIN(w, wb + e, b16);
        ushort hi, lo; split2(x, hi, lo);
        bHi[n * 72 + k] = hi; bLo[n * 72 + k] = lo;
    }
    __syncthreads();

    const int wv = t >> 6, lane = t & 63;
    const int ml = lane & 15, q = lane >> 4;

    short8 bhf[4][2], blf[4][2];
#pragma unroll
    for (int nt = 0; nt < 4; ++nt)
#pragma unroll
        for (int kc = 0; kc < 2; ++kc) {
            int n = nt * 16 + ml, k = kc * 32 + q * 8;
            bhf[nt][kc] = *(const short8*)&bHi[n * 72 + k];
            blf[nt][kc] = *(const short8*)&bLo[n * 72 + k];
        }
    float aS[4], aD[4];
#pragma unroll
    for (int nt = 0; nt < 4; ++nt) {
        aS[nt] = LDIN(asrc, hd * FF + nt * 16 + ml, b16);
        aD[nt] = LDIN(adst, hd * FF + nt * 16 + ml, b16);
    }

    float wmin = 3.4e38f, wmax = -3.4e38f;
    for (int mt = wv; mt < 8; mt += 4) {
        const int rb = mt * 16;
        short8 ah[2], al[2];
#pragma unroll
        for (int kc = 0; kc < 2; ++kc) {
            int k = kc * 32 + q * 8;
            ah[kc] = *(const short8*)&aHi[(rb + ml) * 72 + k];
            al[kc] = *(const short8*)&aLo[(rb + ml) * 72 + k];
        }
        floatx4 acc[4];
#pragma unroll
        for (int nt = 0; nt < 4; ++nt) {
            floatx4 a = {0.f, 0.f, 0.f, 0.f};
#pragma unroll
            for (int kc = 0; kc < 2; ++kc) {
                a = __builtin_amdgcn_mfma_f32_16x16x32_bf16(ah[kc], bhf[nt][kc], a, 0, 0, 0);
                a = __builtin_amdgcn_mfma_f32_16x16x32_bf16(ah[kc], blf[nt][kc], a, 0, 0, 0);
                a = __builtin_amdgcn_mfma_f32_16x16x32_bf16(al[kc], bhf[nt][kc], a, 0, 0, 0);
            }
            acc[nt] = a;
        }
        float ps[4] = {0.f, 0.f, 0.f, 0.f}, pd[4] = {0.f, 0.f, 0.f, 0.f};
#pragma unroll
        for (int nt = 0; nt < 4; ++nt)
#pragma unroll
            for (int reg = 0; reg < 4; ++reg) {
                int row = q * 4 + reg;               // C/D: col=lane&15, row=quad*4+reg
                int i = r0 + rb + row;
                float v = acc[nt][reg];
                hpB[((size_t)bh * NN + i) * FF + nt * 16 + ml] = __float2bfloat16(v);
                float tv = tanhf(v);
                ps[reg] += tv * aS[nt];
                pd[reg] += tv * aD[nt];
            }
#pragma unroll
        for (int msk = 1; msk < 16; msk <<= 1)
#pragma unroll
            for (int reg = 0; reg < 4; ++reg) {
                ps[reg] += __shfl_xor(ps[reg], msk, 64);
                pd[reg] += __shfl_xor(pd[reg], msk, 64);
            }
        if (ml == 0) {
#pragma unroll
            for (int reg = 0; reg < 4; ++reg) {
                int i = r0 + rb + q * 4 + reg;
                sArr[bh * NN + i] = ps[reg];
                dArr[bh * NN + i] = pd[reg];
                wmin = fminf(wmin, pd[reg]);
                wmax = fmaxf(wmax, pd[reg]);
            }
        }
    }
#pragma unroll
    for (int msk = 1; msk < 64; msk <<= 1) {
        wmin = fminf(wmin, __shfl_xor(wmin, msk, 64));
        wmax = fmaxf(wmax, __shfl_xor(wmax, msk, 64));
    }
    if (lane == 0) {
        atomicMin(&mm[2 * bh],     encf(wmin));
        atomicMax(&mm[2 * bh + 1], encf(wmax));
    }
}

// ---- Kernel 2: sort d (bins + per-bin sort), scalar scans, per-row rank/α/β --
__global__ __launch_bounds__(256) void k_bin(
    const float* __restrict__ sArr, const float* __restrict__ dArr,
    const unsigned* __restrict__ mm,
    int* __restrict__ bjG, float* __restrict__ eHG, float* __restrict__ eLG,
    int* __restrict__ chunkRowSt, int* __restrict__ rowIdx,
    float* __restrict__ rowA, float* __restrict__ rowB, int* __restrict__ rowK)
{
    __shared__ float ld[NN];
    __shared__ float s2[NN];
    __shared__ int   j2[NN];
    __shared__ int   hist[NB];
    __shared__ int   hoff[NB + 1];
    __shared__ int   cur[NB];
    __shared__ float eHv[NN];
    __shared__ float eLv[NN];
    __shared__ float pH[NN + 1];
    __shared__ float pL[NN + 1];
    __shared__ int   iw[4];
    __shared__ float fwH[4];
    __shared__ float fwL[4];
    __shared__ int   rhist[NCH2];
    __shared__ int   roff[NCH2 + 1];
    __shared__ int   rcur[NCH2];
    __shared__ int   rKl[NN];
    __shared__ float rAl[NN];
    __shared__ float rBl[NN];

    const int bh = blockIdx.x, t = threadIdx.x;
    const int lane = t & 63, wv = t >> 6;
    const float dmin = decf(mm[2 * bh]);
    const float dmax = decf(mm[2 * bh + 1]);
    const float inv  = (dmax > dmin) ? (float)NB / (dmax - dmin) : 0.f;

    for (int e = t; e < NN; e += 256) ld[e] = dArr[bh * NN + e];
    for (int bb = t; bb < NB; bb += 256) hist[bb] = 0;
    if (t < NCH2) rhist[t] = 0;
    __syncthreads();
    for (int e = t; e < NN; e += 256) atomicAdd(&hist[binOf(ld[e], dmin, inv)], 1);
    __syncthreads();

    // parallel scan hist -> hoff (2 bins/thread)
    {
        int l0 = hist[2 * t], l1 = hist[2 * t + 1];
        int lsum = l0 + l1;
        int incl = wave_iscan(lsum);
        if (lane == 63) iw[wv] = incl;
        __syncthreads();
        int base = 0;
        for (int w2 = 0; w2 < wv; ++w2) base += iw[w2];
        int excl = base + incl - lsum;
        hoff[2 * t] = excl; hoff[2 * t + 1] = excl + l0;
        if (t == 0) hoff[NB] = NN;
    }
    __syncthreads();
    for (int bb = t; bb < NB; bb += 256) cur[bb] = hoff[bb];
    __syncthreads();
    for (int e = t; e < NN; e += 256) {
        int bb = binOf(ld[e], dmin, inv);
        int p = atomicAdd(&cur[bb], 1);
        s2[p] = ld[e]; j2[p] = e;
    }
    __syncthreads();
    for (int bb = t; bb < NB; bb += 256) {      // exact order within each bin
        int st = hoff[bb], en = hoff[bb + 1];
        for (int a2 = st + 1; a2 < en; ++a2) {
            float kv = s2[a2]; int ji = j2[a2]; int b2 = a2 - 1;
            while (b2 >= st && s2[b2] > kv) { s2[b2 + 1] = s2[b2]; j2[b2 + 1] = j2[b2]; --b2; }
            s2[b2 + 1] = kv; j2[b2 + 1] = ji;
        }
    }
    __syncthreads();

    // element weights + block-parallel scalar prefix scans
    {
        float lH = 0.f, lL = 0.f;
#pragma unroll
        for (int r = 0; r < 8; ++r) {
            int m = t * 8 + r;
            float dv = s2[m];
            float a = __expf(dv), b2 = __expf(0.2f * dv);
            eHv[m] = a; eLv[m] = b2; lH += a; lL += b2;
        }
        float inH = wave_fscan(lH);
        float inL = wave_fscan(lL);
        if (lane == 63) { fwH[wv] = inH; fwL[wv] = inL; }
        __syncthreads();
        float bHs = 0.f, bLs = 0.f;
        for (int w2 = 0; w2 < wv; ++w2) { bHs += fwH[w2]; bLs += fwL[w2]; }
        float rH = bHs + inH - lH, rL = bLs + inL - lL;
#pragma unroll
        for (int r = 0; r < 8; ++r) {
            int m = t * 8 + r;
            pH[m] = rH; pL[m] = rL;
            rH += eHv[m]; rL += eLv[m];
        }
        if (t == 255) { pH[NN] = rH; pL[NN] = rL; }
    }
    __syncthreads();
    const float totHs = pH[NN];

    // per-row: rank, alpha, beta  (pass 1: stash in LDS + chunk histogram)
    for (int e = t; e < NN; e += 256) {
        float sv = sArr[bh * NN + e];
        float tau = -sv;
        int bb = binOf(tau, dmin, inv);
        int st = hoff[bb], en = hoff[bb + 1];
        int cnt = 0;
        for (int m = st; m < en; ++m) cnt += (s2[m] < tau) ? 1 : 0;
        int k = st + cnt;
        float es = __expf(sv), es2 = __expf(0.2f * sv);
        float den = es * (totHs - pH[k]) + es2 * pL[k];
        rKl[e] = k; rAl[e] = es / den; rBl[e] = es2 / den;
        int c = k >> 6; if (c > NCH2 - 1) c = NCH2 - 1;
        atomicAdd(&rhist[c], 1);
    }
    __syncthreads();
    if (t == 0) {
        int run = 0;
        for (int c = 0; c < NCH2; ++c) { roff[c] = run; run += rhist[c]; }
        roff[NCH2] = run;
    }
    __syncthreads();
    if (t < NCH2) rcur[t] = roff[t];
    __syncthreads();
    // pass 2: scatter rows grouped by chunk; emit globals
    for (int e = t; e < NN; e += 256) {
        int k = rKl[e];
        int c = k >> 6; if (c > NCH2 - 1) c = NCH2 - 1;
        int p = atomicAdd(&rcur[c], 1);
        rowIdx[bh * NN + p] = e;
        rowA[bh * NN + p] = rAl[e];
        rowB[bh * NN + p] = rBl[e];
        rowK[bh * NN + p] = k;
    }
    for (int e = t; e < NN; e += 256) {
        bjG[bh * NN + e] = j2[e];
        eHG[bh * NN + e] = eHv[e];
        eLG[bh * NN + e] = eLv[e];
    }
    if (t <= NCH2) chunkRowSt[bh * (NCH2 + 1) + t] = roff[t];
}

// ---- Kernel 3: per-chunk vector sums (64 sorted elements each) ---------------
__global__ __launch_bounds__(64) void k_chunkV(
    const int* __restrict__ bjG, const float* __restrict__ eHG, const float* __restrict__ eLG,
    const __hip_bfloat16* __restrict__ hpB,
    float* __restrict__ cHv, float* __restrict__ cLv)
{
    const int bh = blockIdx.x >> 5, c = blockIdx.x & (NCH2 - 1);
    const int o  = threadIdx.x;
    float aH = 0.f, aL = 0.f;
    for (int m0 = 0; m0 < CL; ++m0) {
        const int m = bh * NN + c * CL + m0;
        int j = bjG[m];
        float v = __bfloat162float(hpB[((size_t)bh * NN + j) * FF + o]);
        aH += eHG[m] * v;
        aL += eLG[m] * v;
    }
    cHv[((size_t)bh * NCH2 + c) * FF + o] = aH;
    cLv[((size_t)bh * NCH2 + c) * FF + o] = aL;
}

// ---- Kernel 4: chunk-offset scan (33 entries; index 32 = grand total) --------
__global__ __launch_bounds__(128) void k_scanV(
    const float* __restrict__ cHv, const float* __restrict__ cLv,
    float* __restrict__ oHv, float* __restrict__ oLv)
{
    const int bh = blockIdx.x;
    const int wv = threadIdx.x >> 6, o = threadIdx.x & 63;
    const float* src = wv ? cLv : cHv;
    float* dst = wv ? oLv : oHv;
    float run = 0.f;
    for (int c = 0; c < NCH2; ++c) {
        dst[((size_t)bh * (NCH2 + 1) + c) * FF + o] = run;
        run += src[((size_t)bh * NCH2 + c) * FF + o];
    }
    dst[((size_t)bh * (NCH2 + 1) + NCH2) * FF + o] = run;
}

// ---- Kernel 5: sweep chunk, snapshot prefixes in LDS, emit owned rows --------
__global__ __launch_bounds__(64) void k_emit(
    const int* __restrict__ bjG, const float* __restrict__ eHG, const float* __restrict__ eLG,
    const __hip_bfloat16* __restrict__ hpB,
    const float* __restrict__ oHv, const float* __restrict__ oLv,
    const int* __restrict__ chunkRowSt, const int* __restrict__ rowIdx,
    const float* __restrict__ rowA, const float* __restrict__ rowB,
    const int* __restrict__ rowK,
    const void* __restrict__ bias, const int* __restrict__ flag, void* __restrict__ out)
{
    __shared__ float snapH[CL + 1][FF];
    __shared__ float snapL[CL + 1][FF];

    const int b16 = flag[0];
    const int bh = blockIdx.x >> 5, c = blockIdx.x & (NCH2 - 1);
    const int o  = threadIdx.x;

    float runH = oHv[((size_t)bh * (NCH2 + 1) + c) * FF + o];
    float runL = oLv[((size_t)bh * (NCH2 + 1) + c) * FF + o];
    snapH[0][o] = runH; snapL[0][o] = runL;
    for (int m0 = 0; m0 < CL; ++m0) {
        const int m = bh * NN + c * CL + m0;
        int j = bjG[m];
        float v = __bfloat162float(hpB[((size_t)bh * NN + j) * FF + o]);
        runH += eHG[m] * v;
        runL += eLG[m] * v;
        snapH[m0 + 1][o] = runH;
        snapL[m0 + 1][o] = runL;
    }
    __syncthreads();

    const float TH = oHv[((size_t)bh * (NCH2 + 1) + NCH2) * FF + o];
    const float biasv = LDIN(bias, o, b16);
    const int st = chunkRowSt[bh * (NCH2 + 1) + c];
    const int en = chunkRowSt[bh * (NCH2 + 1) + c + 1];
    for (int pos = st; pos < en; ++pos) {
        int i  = rowIdx[bh * NN + pos];
        float al = rowA[bh * NN + pos];
        float be = rowB[bh * NN + pos];
        int kk = rowK[bh * NN + pos] - c * CL;   // in [0, 64]
        float res = al * (TH - snapH[kk][o]) + be * snapL[kk][o] + biasv;
        const size_t oi = ((size_t)bh * NN + i) * FF + o;
        if (b16) ((__hip_bfloat16*)out)[oi] = __float2bfloat16(res);
        else     ((float*)out)[oi] = res;
    }
}

extern "C" void kernel_launch(void* const* d_in, const int* in_sizes, int n_in,
                              void* d_out, int out_size, void* d_ws, size_t ws_size,
                              hipStream_t stream) {
    const void* h    = d_in[0];
    // d_in[1] = adj (bool) — unused by reference
    const void* w    = d_in[2];
    const void* asrc = d_in[3];
    const void* adst = d_in[4];
    const void* bias = d_in[5];

    float* ws = (float*)d_ws;
    int*      flag = (int*)ws;                               // 4
    unsigned* mm   = (unsigned*)(flag + 4);                  // 64 (+pad to 128)
    __hip_bfloat16* hpB = (__hip_bfloat16*)(ws + 128);       // BH*NN*FF bf16
    float* sArr  = ws + 128 + (size_t)BH * NN * FF / 2;      // BH*NN
    float* dArr  = sArr + BH * NN;
    int*   bjG   = (int*)(dArr + BH * NN);                   // BH*NN
    float* eHG   = (float*)(bjG + BH * NN);
    float* eLG   = eHG + BH * NN;
    float* cHv   = eLG + BH * NN;                            // BH*NCH2*FF
    float* cLv   = cHv + (size_t)BH * NCH2 * FF;
    float* oHv   = cLv + (size_t)BH * NCH2 * FF;             // BH*(NCH2+1)*FF
    float* oLv   = oHv + (size_t)BH * (NCH2 + 1) * FF;
    int*   chunkRowSt = (int*)(oLv + (size_t)BH * (NCH2 + 1) * FF);  // BH*(NCH2+1)
    int*   rowIdx = chunkRowSt + BH * (NCH2 + 1);            // BH*NN
    float* rowA  = (float*)(rowIdx + BH * NN);
    float* rowB  = rowA + BH * NN;
    int*   rowK  = (int*)(rowB + BH * NN);

    k_init<<<1, 64, 0, stream>>>(h, flag, mm);
    k_proj<<<512, 256, 0, stream>>>(h, w, asrc, adst, flag, hpB, sArr, dArr, mm);
    k_bin<<<BH, 256, 0, stream>>>(sArr, dArr, mm, bjG, eHG, eLG,
                                  chunkRowSt, rowIdx, rowA, rowB, rowK);
    k_chunkV<<<BH * NCH2, 64, 0, stream>>>(bjG, eHG, eLG, hpB, cHv, cLv);
    k_scanV<<<BH, 128, 0, stream>>>(cHv, cLv, oHv, oLv);
    k_emit<<<BH * NCH2, 64, 0, stream>>>(bjG, eHG, eLG, hpB, oHv, oLv,
                                         chunkRowSt, rowIdx, rowA, rowB, rowK,
                                         bias, flag, d_out);
}

// Round 6
// 217.916 us; speedup vs baseline: 1.5132x; 1.0088x over previous
//
#include <hip/hip_runtime.h>
#include <hip/hip_bf16.h>

#define NN 2048
#define FF 64
#define NH 8
#define BDIM 4
#define BH 32        // BDIM*NH
#define NB 512       // d-value bins
#define NCH 32       // chunks per (b,head)
#define CL 64        // elements per chunk

typedef __attribute__((ext_vector_type(8))) short short8;
typedef __attribute__((ext_vector_type(4))) float floatx4;
typedef __attribute__((ext_vector_type(4))) unsigned uint4v;

__device__ __forceinline__ float LDIN(const void* p, size_t i, int b16) {
    return b16 ? __bfloat162float(((const __hip_bfloat16*)p)[i]) : ((const float*)p)[i];
}
__device__ __forceinline__ int binOf(float d, float dmin, float inv) {
    int b = (int)((d - dmin) * inv);
    return b < 0 ? 0 : (b > NB - 1 ? NB - 1 : b);
}
__device__ __forceinline__ void split2(float x, ushort& hi, ushort& lo) {
    unsigned u = __float_as_uint(x);
    hi = (ushort)(u >> 16);
    float fl = x - __uint_as_float(u & 0xFFFF0000u);
    lo = (ushort)(__float_as_uint(fl) >> 16);
}
__device__ __forceinline__ int wave_iscan(int v) {
    const int lane = threadIdx.x & 63;
#pragma unroll
    for (int off = 1; off < 64; off <<= 1) {
        int u = __shfl_up(v, off, 64);
        if (lane >= off) v += u;
    }
    return v;
}
__device__ __forceinline__ float wave_fscan(float v) {
    const int lane = threadIdx.x & 63;
#pragma unroll
    for (int off = 1; off < 64; off <<= 1) {
        float u = __shfl_up(v, off, 64);
        if (lane >= off) v += u;
    }
    return v;
}

// ---- Kernel 1: MFMA GEMM hp=h@w (split-bf16 when fp32 input), s/d, sniff ----
// grid 1024: block = (b, hd, 64-row tile). 256 thr = 4 waves, 1 M-tile16 each.
__global__ __launch_bounds__(256) void k_proj(
    const void* __restrict__ h, const void* __restrict__ w,
    const void* __restrict__ asrc, const void* __restrict__ adst,
    __hip_bfloat16* __restrict__ hpB, float* __restrict__ sArr,
    float* __restrict__ dArr, int* __restrict__ flagOut)
{
    const int t  = threadIdx.x;
    const int rt = blockIdx.x & 31;
    const int hd = (blockIdx.x >> 5) & 7;
    const int b  = blockIdx.x >> 8;
    const int bh = b * NH + hd;
    const int r0 = rt * 64;

    __shared__ int sb16;
    if (t < 64) {
        unsigned word = ((const unsigned*)h)[t];
        unsigned lowexp = (word >> 7) & 0xFFu;
        bool plaus = (lowexp >= 96u && lowexp <= 159u);
        unsigned long long m = __ballot(plaus);
        if (t == 0) sb16 = (__popcll(m) >= 48) ? 1 : 0;
    }
    __shared__ ushort bHi[64 * 72];     // transposed w: bHi[n][k], stride 72
    __shared__ ushort bLo[64 * 72];
    __syncthreads();
    const int b16 = sb16;
    if (blockIdx.x == 0 && t == 0) flagOut[0] = b16;

    if (b16) {
        const ushort* wp = (const ushort*)w + (size_t)hd * FF * FF;
        for (int e4 = t; e4 < 1024; e4 += 256) {     // 4 bf16 per iter
            uint2 u = *(const uint2*)(wp + e4 * 4);
            int e = e4 * 4, k = e >> 6, n = e & 63;
            bHi[(n + 0) * 72 + k] = (ushort)(u.x & 0xFFFF);
            bHi[(n + 1) * 72 + k] = (ushort)(u.x >> 16);
            bHi[(n + 2) * 72 + k] = (ushort)(u.y & 0xFFFF);
            bHi[(n + 3) * 72 + k] = (ushort)(u.y >> 16);
        }
    } else {
        const float* wp = (const float*)w + (size_t)hd * FF * FF;
        for (int e4 = t; e4 < 1024; e4 += 256) {
            floatx4 x = *(const floatx4*)(wp + e4 * 4);
            int e = e4 * 4, k = e >> 6, n = e & 63;
#pragma unroll
            for (int r = 0; r < 4; ++r) {
                ushort hi, lo; split2(x[r], hi, lo);
                bHi[(n + r) * 72 + k] = hi;
                bLo[(n + r) * 72 + k] = lo;
            }
        }
    }
    __syncthreads();

    const int wv = t >> 6, lane = t & 63;
    const int ml = lane & 15, q = lane >> 4;
    const int grow = b * NN + r0 + wv * 16 + ml;     // this lane's A row

    short8 ah[2], al[2];
    if (b16) {
        const ushort* hp16 = (const ushort*)h;
#pragma unroll
        for (int kc = 0; kc < 2; ++kc) {
            uint4v u = *(const uint4v*)(hp16 + (size_t)grow * FF + kc * 32 + q * 8);
            ah[kc] = __builtin_bit_cast(short8, u);
        }
    } else {
        const float* hpf = (const float*)h;
#pragma unroll
        for (int kc = 0; kc < 2; ++kc) {
            floatx4 x0 = *(const floatx4*)(hpf + (size_t)grow * FF + kc * 32 + q * 8);
            floatx4 x1 = *(const floatx4*)(hpf + (size_t)grow * FF + kc * 32 + q * 8 + 4);
            short8 H, L;
#pragma unroll
            for (int r = 0; r < 4; ++r) {
                ushort hi, lo;
                split2(x0[r], hi, lo); H[r] = (short)hi; L[r] = (short)lo;
                split2(x1[r], hi, lo); H[4 + r] = (short)hi; L[4 + r] = (short)lo;
            }
            ah[kc] = H; al[kc] = L;
        }
    }

    short8 bhf[4][2], blf[4][2];
#pragma unroll
    for (int nt = 0; nt < 4; ++nt)
#pragma unroll
        for (int kc = 0; kc < 2; ++kc) {
            int n = nt * 16 + ml, k = kc * 32 + q * 8;
            bhf[nt][kc] = *(const short8*)&bHi[n * 72 + k];
            if (!b16) blf[nt][kc] = *(const short8*)&bLo[n * 72 + k];
        }

    float aS[4], aD[4];
#pragma unroll
    for (int nt = 0; nt < 4; ++nt) {
        aS[nt] = LDIN(asrc, hd * FF + nt * 16 + ml, b16);
        aD[nt] = LDIN(adst, hd * FF + nt * 16 + ml, b16);
    }

    floatx4 acc[4];
#pragma unroll
    for (int nt = 0; nt < 4; ++nt) {
        floatx4 a = {0.f, 0.f, 0.f, 0.f};
        if (b16) {
#pragma unroll
            for (int kc = 0; kc < 2; ++kc)
                a = __builtin_amdgcn_mfma_f32_16x16x32_bf16(ah[kc], bhf[nt][kc], a, 0, 0, 0);
        } else {
#pragma unroll
            for (int kc = 0; kc < 2; ++kc) {
                a = __builtin_amdgcn_mfma_f32_16x16x32_bf16(ah[kc], bhf[nt][kc], a, 0, 0, 0);
                a = __builtin_amdgcn_mfma_f32_16x16x32_bf16(ah[kc], blf[nt][kc], a, 0, 0, 0);
                a = __builtin_amdgcn_mfma_f32_16x16x32_bf16(al[kc], bhf[nt][kc], a, 0, 0, 0);
            }
        }
        acc[nt] = a;
    }

    float ps[4] = {0.f, 0.f, 0.f, 0.f}, pd[4] = {0.f, 0.f, 0.f, 0.f};
#pragma unroll
    for (int nt = 0; nt < 4; ++nt)
#pragma unroll
        for (int reg = 0; reg < 4; ++reg) {
            int i = r0 + wv * 16 + q * 4 + reg;      // C/D: col=lane&15, row=q*4+reg
            float v = acc[nt][reg];
            hpB[((size_t)bh * NN + i) * FF + nt * 16 + ml] = __float2bfloat16(v);
            float tv = tanhf(v);
            ps[reg] += tv * aS[nt];
            pd[reg] += tv * aD[nt];
        }
#pragma unroll
    for (int msk = 1; msk < 16; msk <<= 1)
#pragma unroll
        for (int reg = 0; reg < 4; ++reg) {
            ps[reg] += __shfl_xor(ps[reg], msk, 64);
            pd[reg] += __shfl_xor(pd[reg], msk, 64);
        }
    if (ml == 0) {
#pragma unroll
        for (int reg = 0; reg < 4; ++reg) {
            int i = r0 + wv * 16 + q * 4 + reg;
            sArr[bh * NN + i] = ps[reg];
            dArr[bh * NN + i] = pd[reg];
        }
    }
}

// ---- Kernel 2: sort d by bins, scalar scans, per-row cut k/α/β sorted by k ---
__global__ __launch_bounds__(512) void k_bin(
    const float* __restrict__ sArr, const float* __restrict__ dArr,
    int* __restrict__ bjG, float* __restrict__ eHG, float* __restrict__ eLG,
    int* __restrict__ rowIdx, float* __restrict__ rowA, float* __restrict__ rowB,
    int* __restrict__ rowK, int* __restrict__ chunkRowSt)
{
    __shared__ float ld[NN];
    __shared__ float s2[NN];
    __shared__ int   j2[NN];
    __shared__ int   hist[NB];
    __shared__ int   hoff[NB + 1];
    __shared__ int   cur[NB];
    __shared__ float eHv[NN];
    __shared__ float eLv[NN];
    __shared__ float pH[NN + 1];
    __shared__ float pL[NN + 1];
    __shared__ int   khist[NN + 1];
    __shared__ int   koff[NN + 1];
    __shared__ int   iw[8];
    __shared__ float fwH[8];
    __shared__ float fwL[8];
    __shared__ float redmin[8], redmax[8];

    const int bh = blockIdx.x, t = threadIdx.x;
    const int lane = t & 63, wv = t >> 6;

    float lmin = 3.4e38f, lmax = -3.4e38f;
    for (int e = t; e < NN; e += 512) {
        float v = dArr[bh * NN + e];
        ld[e] = v;
        lmin = fminf(lmin, v); lmax = fmaxf(lmax, v);
    }
#pragma unroll
    for (int msk = 1; msk < 64; msk <<= 1) {
        lmin = fminf(lmin, __shfl_xor(lmin, msk, 64));
        lmax = fmaxf(lmax, __shfl_xor(lmax, msk, 64));
    }
    if (lane == 0) { redmin[wv] = lmin; redmax[wv] = lmax; }
    for (int bb = t; bb < NB; bb += 512) hist[bb] = 0;
    for (int k = t; k <= NN; k += 512) khist[k] = 0;
    __syncthreads();
    float dmin = redmin[0], dmax = redmax[0];
#pragma unroll
    for (int w2 = 1; w2 < 8; ++w2) {
        dmin = fminf(dmin, redmin[w2]); dmax = fmaxf(dmax, redmax[w2]);
    }
    const float inv = (dmax > dmin) ? (float)NB / (dmax - dmin) : 0.f;

    for (int e = t; e < NN; e += 512) atomicAdd(&hist[binOf(ld[e], dmin, inv)], 1);
    __syncthreads();
    {   // scan hist -> hoff (1 bin/thread)
        int lsum = hist[t];
        int incl = wave_iscan(lsum);
        if (lane == 63) iw[wv] = incl;
        __syncthreads();
        int base = 0;
        for (int w2 = 0; w2 < wv; ++w2) base += iw[w2];
        hoff[t] = base + incl - lsum;
        if (t == 511) hoff[NB] = NN;
    }
    __syncthreads();
    cur[t] = hoff[t];
    __syncthreads();
    for (int e = t; e < NN; e += 512) {
        int bb = binOf(ld[e], dmin, inv);
        int p = atomicAdd(&cur[bb], 1);
        s2[p] = ld[e]; j2[p] = e;
    }
    __syncthreads();
    {   // exact order within each bin (1 bin/thread)
        int st = hoff[t], en = hoff[t + 1];
        for (int a2 = st + 1; a2 < en; ++a2) {
            float kv = s2[a2]; int ji = j2[a2]; int b2 = a2 - 1;
            while (b2 >= st && s2[b2] > kv) { s2[b2 + 1] = s2[b2]; j2[b2 + 1] = j2[b2]; --b2; }
            s2[b2 + 1] = kv; j2[b2 + 1] = ji;
        }
    }
    __syncthreads();
    {   // element weights + block-parallel scalar prefix scans (4 elems/thread)
        float lH = 0.f, lL = 0.f;
#pragma unroll
        for (int r = 0; r < 4; ++r) {
            int m = t * 4 + r;
            float dv = s2[m];
            float a = __expf(dv), b2 = __expf(0.2f * dv);
            eHv[m] = a; eLv[m] = b2; lH += a; lL += b2;
        }
        float inH = wave_fscan(lH);
        float inL = wave_fscan(lL);
        if (lane == 63) { fwH[wv] = inH; fwL[wv] = inL; }
        __syncthreads();
        float bHs = 0.f, bLs = 0.f;
        for (int w2 = 0; w2 < wv; ++w2) { bHs += fwH[w2]; bLs += fwL[w2]; }
        float rH = bHs + inH - lH, rL = bLs + inL - lL;
#pragma unroll
        for (int r = 0; r < 4; ++r) {
            int m = t * 4 + r;
            pH[m] = rH; pL[m] = rL;
            rH += eHv[m]; rL += eLv[m];
        }
        if (t == 511) { pH[NN] = rH; pL[NN] = rL; }
    }
    __syncthreads();

    // pass 1: per-row cut k (exact rank), k-histogram; cache s in ld
    for (int e = t; e < NN; e += 512) {
        float sv = sArr[bh * NN + e];
        ld[e] = sv;
        float tau = -sv;
        int bb = binOf(tau, dmin, inv);
        int st = hoff[bb], en = hoff[bb + 1];
        int cnt = 0;
        for (int m = st; m < en; ++m) cnt += (s2[m] < tau) ? 1 : 0;
        atomicAdd(&khist[st + cnt], 1);
    }
    __syncthreads();
    {   // scan khist[0..2047] -> koff (4/thread); koff[2048]=total
        int l0 = khist[4 * t], l1 = khist[4 * t + 1],
            l2 = khist[4 * t + 2], l3 = khist[4 * t + 3];
        int lsum = l0 + l1 + l2 + l3;
        int incl = wave_iscan(lsum);
        if (lane == 63) iw[wv] = incl;
        __syncthreads();
        int base = 0;
        for (int w2 = 0; w2 < wv; ++w2) base += iw[w2];
        int excl = base + incl - lsum;
        koff[4 * t] = excl;
        koff[4 * t + 1] = excl + l0;
        koff[4 * t + 2] = excl + l0 + l1;
        koff[4 * t + 3] = excl + l0 + l1 + l2;
        if (t == 511) koff[NN] = excl + lsum;
    }
    __syncthreads();
    for (int k = t; k <= NN; k += 512) khist[k] = koff[k];   // khist becomes cursor
    __syncthreads();
    const float totH = pH[NN];
    // pass 2: recompute α/β, counting-scatter rows sorted by k
    for (int e = t; e < NN; e += 512) {
        float sv = ld[e];
        float tau = -sv;
        int bb = binOf(tau, dmin, inv);
        int st = hoff[bb], en = hoff[bb + 1];
        int cnt = 0;
        for (int m = st; m < en; ++m) cnt += (s2[m] < tau) ? 1 : 0;
        int k = st + cnt;
        float es = __expf(sv), es2 = __expf(0.2f * sv);
        float den = es * (totH - pH[k]) + es2 * pL[k];
        int p = atomicAdd(&khist[k], 1);
        rowIdx[bh * NN + p] = e;
        rowA[bh * NN + p] = es / den;
        rowB[bh * NN + p] = es2 / den;
        rowK[bh * NN + p] = k;
    }
    for (int e = t; e < NN; e += 512) {
        bjG[bh * NN + e] = j2[e];
        eHG[bh * NN + e] = eHv[e];
        eLG[bh * NN + e] = eLv[e];
    }
    for (int c = t; c < NCH + 1; c += 512)
        chunkRowSt[bh * (NCH + 1) + c] = (c < NCH) ? koff[c * CL] : NN;
}

// ---- Kernel 3: per-bh chunk sums + in-block scan -> chunk offset vectors -----
__global__ __launch_bounds__(1024) void k_sum(
    const int* __restrict__ bjG, const float* __restrict__ eHG, const float* __restrict__ eLG,
    const __hip_bfloat16* __restrict__ hpB,
    float* __restrict__ oHv, float* __restrict__ oLv)
{
    __shared__ float csH[NCH][FF];
    __shared__ float csL[NCH][FF];
    const int bh = blockIdx.x;
    const int wv = threadIdx.x >> 6, o = threadIdx.x & 63;

    for (int c = wv; c < NCH; c += 16) {
        float aH = 0.f, aL = 0.f;
#pragma unroll 8
        for (int m0 = 0; m0 < CL; ++m0) {
            const int m = bh * NN + c * CL + m0;
            int j = bjG[m];
            float v = __bfloat162float(hpB[((size_t)bh * NN + j) * FF + o]);
            aH += eHG[m] * v;
            aL += eLG[m] * v;
        }
        csH[c][o] = aH; csL[c][o] = aL;
    }
    __syncthreads();
    if (wv == 0) {
        float run = 0.f;
        for (int c = 0; c < NCH; ++c) {
            oHv[((size_t)bh * (NCH + 1) + c) * FF + o] = run;
            run += csH[c][o];
        }
        oHv[((size_t)bh * (NCH + 1) + NCH) * FF + o] = run;   // TH
    } else if (wv == 1) {
        float run = 0.f;
        for (int c = 0; c < NCH; ++c) {
            oLv[((size_t)bh * (NCH + 1) + c) * FF + o] = run;
            run += csL[c][o];
        }
        oLv[((size_t)bh * (NCH + 1) + NCH) * FF + o] = run;
    }
}

// ---- Kernel 4: ordered chunk sweep, emit rows inline at their cut ------------
__global__ __launch_bounds__(256) void k_emit(
    const int* __restrict__ bjG, const float* __restrict__ eHG, const float* __restrict__ eLG,
    const __hip_bfloat16* __restrict__ hpB,
    const float* __restrict__ oHv, const float* __restrict__ oLv,
    const int* __restrict__ chunkRowSt, const int* __restrict__ rowIdx,
    const float* __restrict__ rowA, const float* __restrict__ rowB,
    const int* __restrict__ rowK,
    const void* __restrict__ bias, const int* __restrict__ flag, void* __restrict__ out)
{
    const int b16 = flag[0];
    const int wv = threadIdx.x >> 6, o = threadIdx.x & 63;
    const int cid = blockIdx.x * 4 + wv;
    const int bh = cid >> 5, c = cid & (NCH - 1);

    float runH = oHv[((size_t)bh * (NCH + 1) + c) * FF + o];
    float runL = oLv[((size_t)bh * (NCH + 1) + c) * FF + o];
    const float TH = oHv[((size_t)bh * (NCH + 1) + NCH) * FF + o];
    const float biasv = LDIN(bias, o, b16);

    int pos = chunkRowSt[bh * (NCH + 1) + c];
    const int en = chunkRowSt[bh * (NCH + 1) + c + 1];

    for (int bt = 0; bt < 4; ++bt) {
        float vb[16], e1b[16], e2b[16];
#pragma unroll
        for (int r = 0; r < 16; ++r) {
            const int m = bh * NN + c * CL + bt * 16 + r;
            int j = bjG[m];
            vb[r] = __bfloat162float(hpB[((size_t)bh * NN + j) * FF + o]);
            e1b[r] = eHG[m]; e2b[r] = eLG[m];
        }
#pragma unroll
        for (int r = 0; r < 16; ++r) {
            const int km = c * CL + bt * 16 + r;
            while (pos < en && rowK[bh * NN + pos] == km) {
                int i = rowIdx[bh * NN + pos];
                float al = rowA[bh * NN + pos], be = rowB[bh * NN + pos];
                float res = al * (TH - runH) + be * runL + biasv;
                const size_t oi = ((size_t)bh * NN + i) * FF + o;
                if (b16) ((__hip_bfloat16*)out)[oi] = __float2bfloat16(res);
                else     ((float*)out)[oi] = res;
                ++pos;
            }
            runH += e1b[r] * vb[r];
            runL += e2b[r] * vb[r];
        }
    }
    while (pos < en) {        // rows with k at/after chunk end (incl. k==NN)
        int i = rowIdx[bh * NN + pos];
        float al = rowA[bh * NN + pos], be = rowB[bh * NN + pos];
        float res = al * (TH - runH) + be * runL + biasv;
        const size_t oi = ((size_t)bh * NN + i) * FF + o;
        if (b16) ((__hip_bfloat16*)out)[oi] = __float2bfloat16(res);
        else     ((float*)out)[oi] = res;
        ++pos;
    }
}

extern "C" void kernel_launch(void* const* d_in, const int* in_sizes, int n_in,
                              void* d_out, int out_size, void* d_ws, size_t ws_size,
                              hipStream_t stream) {
    const void* h    = d_in[0];
    // d_in[1] = adj (bool) — unused by reference
    const void* w    = d_in[2];
    const void* asrc = d_in[3];
    const void* adst = d_in[4];
    const void* bias = d_in[5];

    float* ws = (float*)d_ws;
    int*   flag = (int*)ws;                               // 16 ints (pad/align)
    __hip_bfloat16* hpB = (__hip_bfloat16*)(ws + 16);     // BH*NN*FF bf16
    float* sArr = ws + 16 + (size_t)BH * NN * FF / 2;     // BH*NN
    float* dArr = sArr + BH * NN;
    int*   bjG  = (int*)(dArr + BH * NN);                 // BH*NN
    float* eHG  = (float*)(bjG + BH * NN);
    float* eLG  = eHG + BH * NN;
    int*   rowIdx = (int*)(eLG + BH * NN);                // BH*NN
    float* rowA = (float*)(rowIdx + BH * NN);
    float* rowB = rowA + BH * NN;
    int*   rowK = (int*)(rowB + BH * NN);
    int*   chunkRowSt = rowK + BH * NN;                   // BH*(NCH+1)
    float* oHv  = (float*)(chunkRowSt + BH * (NCH + 1));  // BH*(NCH+1)*FF
    float* oLv  = oHv + (size_t)BH * (NCH + 1) * FF;

    k_proj<<<BDIM * NH * 32, 256, 0, stream>>>(h, w, asrc, adst, hpB, sArr, dArr, flag);
    k_bin<<<BH, 512, 0, stream>>>(sArr, dArr, bjG, eHG, eLG,
                                  rowIdx, rowA, rowB, rowK, chunkRowSt);
    k_sum<<<BH, 1024, 0, stream>>>(bjG, eHG, eLG, hpB, oHv, oLv);
    k_emit<<<BH * NCH / 4, 256, 0, stream>>>(bjG, eHG, eLG, hpB, oHv, oLv,
                                             chunkRowSt, rowIdx, rowA, rowB, rowK,
                                             bias, flag, d_out);
}

// Round 7
// 179.150 us; speedup vs baseline: 1.8407x; 1.2164x over previous
//
#include <hip/hip_runtime.h>
#include <hip/hip_bf16.h>

#define NN 2048
#define FF 64
#define NH 8
#define BDIM 4
#define BH 32        // BDIM*NH
#define NB 1024      // d-value bins
#define NCH 64       // chunks per (b,head)
#define CL 32        // elements per chunk

typedef __attribute__((ext_vector_type(8))) short short8;
typedef __attribute__((ext_vector_type(4))) float floatx4;
typedef __attribute__((ext_vector_type(4))) unsigned uint4v;

__device__ __forceinline__ float LDIN(const void* p, size_t i, int b16) {
    return b16 ? __bfloat162float(((const __hip_bfloat16*)p)[i]) : ((const float*)p)[i];
}
__device__ __forceinline__ int binOf(float d, float dmin, float inv) {
    int b = (int)((d - dmin) * inv);
    return b < 0 ? 0 : (b > NB - 1 ? NB - 1 : b);
}
__device__ __forceinline__ void split2(float x, ushort& hi, ushort& lo) {
    unsigned u = __float_as_uint(x);
    hi = (ushort)(u >> 16);
    float fl = x - __uint_as_float(u & 0xFFFF0000u);
    lo = (ushort)(__float_as_uint(fl) >> 16);
}
__device__ __forceinline__ int wave_iscan(int v) {
    const int lane = threadIdx.x & 63;
#pragma unroll
    for (int off = 1; off < 64; off <<= 1) {
        int u = __shfl_up(v, off, 64);
        if (lane >= off) v += u;
    }
    return v;
}
__device__ __forceinline__ float wave_fscan(float v) {
    const int lane = threadIdx.x & 63;
#pragma unroll
    for (int off = 1; off < 64; off <<= 1) {
        float u = __shfl_up(v, off, 64);
        if (lane >= off) v += u;
    }
    return v;
}

// ---- Kernel 1: MFMA GEMM hp=h@w (split-bf16 when fp32 input), s/d, sniff ----
__global__ __launch_bounds__(256) void k_proj(
    const void* __restrict__ h, const void* __restrict__ w,
    const void* __restrict__ asrc, const void* __restrict__ adst,
    __hip_bfloat16* __restrict__ hpB, float* __restrict__ sArr,
    float* __restrict__ dArr, int* __restrict__ flagOut)
{
    const int t  = threadIdx.x;
    const int rt = blockIdx.x & 31;
    const int hd = (blockIdx.x >> 5) & 7;
    const int b  = blockIdx.x >> 8;
    const int bh = b * NH + hd;
    const int r0 = rt * 64;

    __shared__ int sb16;
    if (t < 64) {
        unsigned word = ((const unsigned*)h)[t];
        unsigned lowexp = (word >> 7) & 0xFFu;
        bool plaus = (lowexp >= 96u && lowexp <= 159u);
        unsigned long long m = __ballot(plaus);
        if (t == 0) sb16 = (__popcll(m) >= 48) ? 1 : 0;
    }
    __shared__ ushort bHi[64 * 72];     // transposed w: bHi[n][k], stride 72
    __shared__ ushort bLo[64 * 72];
    __syncthreads();
    const int b16 = sb16;
    if (blockIdx.x == 0 && t == 0) flagOut[0] = b16;

    if (b16) {
        const ushort* wp = (const ushort*)w + (size_t)hd * FF * FF;
        for (int e4 = t; e4 < 1024; e4 += 256) {
            uint2 u = *(const uint2*)(wp + e4 * 4);
            int e = e4 * 4, k = e >> 6, n = e & 63;
            bHi[(n + 0) * 72 + k] = (ushort)(u.x & 0xFFFF);
            bHi[(n + 1) * 72 + k] = (ushort)(u.x >> 16);
            bHi[(n + 2) * 72 + k] = (ushort)(u.y & 0xFFFF);
            bHi[(n + 3) * 72 + k] = (ushort)(u.y >> 16);
        }
    } else {
        const float* wp = (const float*)w + (size_t)hd * FF * FF;
        for (int e4 = t; e4 < 1024; e4 += 256) {
            floatx4 x = *(const floatx4*)(wp + e4 * 4);
            int e = e4 * 4, k = e >> 6, n = e & 63;
#pragma unroll
            for (int r = 0; r < 4; ++r) {
                ushort hi, lo; split2(x[r], hi, lo);
                bHi[(n + r) * 72 + k] = hi;
                bLo[(n + r) * 72 + k] = lo;
            }
        }
    }
    __syncthreads();

    const int wv = t >> 6, lane = t & 63;
    const int ml = lane & 15, q = lane >> 4;
    const int grow = b * NN + r0 + wv * 16 + ml;

    short8 ah[2], al[2];
    if (b16) {
        const ushort* hp16 = (const ushort*)h;
#pragma unroll
        for (int kc = 0; kc < 2; ++kc) {
            uint4v u = *(const uint4v*)(hp16 + (size_t)grow * FF + kc * 32 + q * 8);
            ah[kc] = __builtin_bit_cast(short8, u);
        }
    } else {
        const float* hpf = (const float*)h;
#pragma unroll
        for (int kc = 0; kc < 2; ++kc) {
            floatx4 x0 = *(const floatx4*)(hpf + (size_t)grow * FF + kc * 32 + q * 8);
            floatx4 x1 = *(const floatx4*)(hpf + (size_t)grow * FF + kc * 32 + q * 8 + 4);
            short8 H, L;
#pragma unroll
            for (int r = 0; r < 4; ++r) {
                ushort hi, lo;
                split2(x0[r], hi, lo); H[r] = (short)hi; L[r] = (short)lo;
                split2(x1[r], hi, lo); H[4 + r] = (short)hi; L[4 + r] = (short)lo;
            }
            ah[kc] = H; al[kc] = L;
        }
    }

    short8 bhf[4][2], blf[4][2];
#pragma unroll
    for (int nt = 0; nt < 4; ++nt)
#pragma unroll
        for (int kc = 0; kc < 2; ++kc) {
            int n = nt * 16 + ml, k = kc * 32 + q * 8;
            bhf[nt][kc] = *(const short8*)&bHi[n * 72 + k];
            if (!b16) blf[nt][kc] = *(const short8*)&bLo[n * 72 + k];
        }

    float aS[4], aD[4];
#pragma unroll
    for (int nt = 0; nt < 4; ++nt) {
        aS[nt] = LDIN(asrc, hd * FF + nt * 16 + ml, b16);
        aD[nt] = LDIN(adst, hd * FF + nt * 16 + ml, b16);
    }

    floatx4 acc[4];
#pragma unroll
    for (int nt = 0; nt < 4; ++nt) {
        floatx4 a = {0.f, 0.f, 0.f, 0.f};
        if (b16) {
#pragma unroll
            for (int kc = 0; kc < 2; ++kc)
                a = __builtin_amdgcn_mfma_f32_16x16x32_bf16(ah[kc], bhf[nt][kc], a, 0, 0, 0);
        } else {
#pragma unroll
            for (int kc = 0; kc < 2; ++kc) {
                a = __builtin_amdgcn_mfma_f32_16x16x32_bf16(ah[kc], bhf[nt][kc], a, 0, 0, 0);
                a = __builtin_amdgcn_mfma_f32_16x16x32_bf16(ah[kc], blf[nt][kc], a, 0, 0, 0);
                a = __builtin_amdgcn_mfma_f32_16x16x32_bf16(al[kc], bhf[nt][kc], a, 0, 0, 0);
            }
        }
        acc[nt] = a;
    }

    float ps[4] = {0.f, 0.f, 0.f, 0.f}, pd[4] = {0.f, 0.f, 0.f, 0.f};
#pragma unroll
    for (int nt = 0; nt < 4; ++nt)
#pragma unroll
        for (int reg = 0; reg < 4; ++reg) {
            int i = r0 + wv * 16 + q * 4 + reg;      // C/D: col=lane&15, row=q*4+reg
            float v = acc[nt][reg];
            hpB[((size_t)bh * NN + i) * FF + nt * 16 + ml] = __float2bfloat16(v);
            float tv = tanhf(v);
            ps[reg] += tv * aS[nt];
            pd[reg] += tv * aD[nt];
        }
#pragma unroll
    for (int msk = 1; msk < 16; msk <<= 1)
#pragma unroll
        for (int reg = 0; reg < 4; ++reg) {
            ps[reg] += __shfl_xor(ps[reg], msk, 64);
            pd[reg] += __shfl_xor(pd[reg], msk, 64);
        }
    if (ml == 0) {
#pragma unroll
        for (int reg = 0; reg < 4; ++reg) {
            int i = r0 + wv * 16 + q * 4 + reg;
            sArr[bh * NN + i] = ps[reg];
            dArr[bh * NN + i] = pd[reg];
        }
    }
}

// ---- Kernel 2: sort d by bins, scalar scans, per-row cut k/α/β sorted by k ---
__global__ __launch_bounds__(1024) void k_bin(
    const float* __restrict__ sArr, const float* __restrict__ dArr,
    int* __restrict__ bjG, float* __restrict__ eHG, float* __restrict__ eLG,
    int* __restrict__ rowIdx, float* __restrict__ rowA, float* __restrict__ rowB,
    int* __restrict__ rowK, int* __restrict__ chunkRowSt)
{
    __shared__ float ld[NN];
    __shared__ float s2[NN];
    __shared__ int   j2[NN];
    __shared__ int   hist[NB];
    __shared__ int   hoff[NB + 1];
    __shared__ int   cur[NB];
    __shared__ float eHv[NN];
    __shared__ float eLv[NN];
    __shared__ float pH[NN + 1];
    __shared__ float pL[NN + 1];
    __shared__ int   khist[NN + 1];
    __shared__ int   koff[NN + 1];
    __shared__ int   rKl[NN];
    __shared__ int   iw[16];
    __shared__ float fwH[16];
    __shared__ float fwL[16];
    __shared__ float redmin[16], redmax[16];

    const int bh = blockIdx.x, t = threadIdx.x;
    const int lane = t & 63, wv = t >> 6;

    float lmin = 3.4e38f, lmax = -3.4e38f;
    for (int e = t; e < NN; e += 1024) {
        float v = dArr[bh * NN + e];
        ld[e] = v;
        lmin = fminf(lmin, v); lmax = fmaxf(lmax, v);
    }
#pragma unroll
    for (int msk = 1; msk < 64; msk <<= 1) {
        lmin = fminf(lmin, __shfl_xor(lmin, msk, 64));
        lmax = fmaxf(lmax, __shfl_xor(lmax, msk, 64));
    }
    if (lane == 0) { redmin[wv] = lmin; redmax[wv] = lmax; }
    hist[t] = 0;
    for (int k = t; k <= NN; k += 1024) khist[k] = 0;
    __syncthreads();
    float dmin = redmin[0], dmax = redmax[0];
#pragma unroll
    for (int w2 = 1; w2 < 16; ++w2) {
        dmin = fminf(dmin, redmin[w2]); dmax = fmaxf(dmax, redmax[w2]);
    }
    const float inv = (dmax > dmin) ? (float)NB / (dmax - dmin) : 0.f;

    for (int e = t; e < NN; e += 1024) atomicAdd(&hist[binOf(ld[e], dmin, inv)], 1);
    __syncthreads();
    {   // scan hist -> hoff (1 bin/thread)
        int lsum = hist[t];
        int incl = wave_iscan(lsum);
        if (lane == 63) iw[wv] = incl;
        __syncthreads();
        int base = 0;
        for (int w2 = 0; w2 < wv; ++w2) base += iw[w2];
        hoff[t] = base + incl - lsum;
        if (t == 1023) hoff[NB] = NN;
    }
    __syncthreads();
    cur[t] = hoff[t];
    __syncthreads();
    for (int e = t; e < NN; e += 1024) {
        int bb = binOf(ld[e], dmin, inv);
        int p = atomicAdd(&cur[bb], 1);
        s2[p] = ld[e]; j2[p] = e;
    }
    __syncthreads();
    {   // exact order within each bin (1 bin/thread, avg 2 elems)
        int st = hoff[t], en = hoff[t + 1];
        for (int a2 = st + 1; a2 < en; ++a2) {
            float kv = s2[a2]; int ji = j2[a2]; int b2 = a2 - 1;
            while (b2 >= st && s2[b2] > kv) { s2[b2 + 1] = s2[b2]; j2[b2 + 1] = j2[b2]; --b2; }
            s2[b2 + 1] = kv; j2[b2 + 1] = ji;
        }
    }
    __syncthreads();
    {   // element weights + block-parallel scalar prefix scans (2 elems/thread)
        float lH = 0.f, lL = 0.f;
#pragma unroll
        for (int r = 0; r < 2; ++r) {
            int m = t * 2 + r;
            float dv = s2[m];
            float a = __expf(dv), b2 = __expf(0.2f * dv);
            eHv[m] = a; eLv[m] = b2; lH += a; lL += b2;
        }
        float inH = wave_fscan(lH);
        float inL = wave_fscan(lL);
        if (lane == 63) { fwH[wv] = inH; fwL[wv] = inL; }
        __syncthreads();
        float bHs = 0.f, bLs = 0.f;
        for (int w2 = 0; w2 < wv; ++w2) { bHs += fwH[w2]; bLs += fwL[w2]; }
        float rH = bHs + inH - lH, rL = bLs + inL - lL;
#pragma unroll
        for (int r = 0; r < 2; ++r) {
            int m = t * 2 + r;
            pH[m] = rH; pL[m] = rL;
            rH += eHv[m]; rL += eLv[m];
        }
        if (t == 1023) { pH[NN] = rH; pL[NN] = rL; }
    }
    __syncthreads();

    // pass 1: per-row cut k (exact rank), store rank, k-histogram; cache s in ld
    for (int e = t; e < NN; e += 1024) {
        float sv = sArr[bh * NN + e];
        ld[e] = sv;
        float tau = -sv;
        int bb = binOf(tau, dmin, inv);
        int st = hoff[bb], en = hoff[bb + 1];
        int cnt = 0;
        for (int m = st; m < en; ++m) cnt += (s2[m] < tau) ? 1 : 0;
        int k = st + cnt;
        rKl[e] = k;
        atomicAdd(&khist[k], 1);
    }
    __syncthreads();
    {   // scan khist[0..2047] -> koff (2/thread); koff[2048]=rows with k<2048
        int l0 = khist[2 * t], l1 = khist[2 * t + 1];
        int lsum = l0 + l1;
        int incl = wave_iscan(lsum);
        if (lane == 63) iw[wv] = incl;
        __syncthreads();
        int base = 0;
        for (int w2 = 0; w2 < wv; ++w2) base += iw[w2];
        int excl = base + incl - lsum;
        koff[2 * t] = excl;
        koff[2 * t + 1] = excl + l0;
        if (t == 1023) koff[NN] = excl + lsum;
    }
    __syncthreads();
    for (int k = t; k <= NN; k += 1024) khist[k] = koff[k];   // cursor
    __syncthreads();
    const float totH = pH[NN];
    // pass 2: α/β, counting-scatter rows sorted by k
    for (int e = t; e < NN; e += 1024) {
        float sv = ld[e];
        int k = rKl[e];
        float es = __expf(sv), es2 = __expf(0.2f * sv);
        float den = es * (totH - pH[k]) + es2 * pL[k];
        int p = atomicAdd(&khist[k], 1);
        rowIdx[bh * NN + p] = e;
        rowA[bh * NN + p] = es / den;
        rowB[bh * NN + p] = es2 / den;
        rowK[bh * NN + p] = k;
    }
    for (int e = t; e < NN; e += 1024) {
        bjG[bh * NN + e] = j2[e];
        eHG[bh * NN + e] = eHv[e];
        eLG[bh * NN + e] = eLv[e];
    }
    for (int c = t; c < NCH + 1; c += 1024)
        chunkRowSt[bh * (NCH + 1) + c] = (c < NCH) ? koff[c * CL] : NN;
}

// ---- Kernel 3: per-bh chunk sums + in-block scan -> chunk offset vectors -----
__global__ __launch_bounds__(1024) void k_sum(
    const int* __restrict__ bjG, const float* __restrict__ eHG, const float* __restrict__ eLG,
    const __hip_bfloat16* __restrict__ hpB,
    float* __restrict__ oHv, float* __restrict__ oLv)
{
    __shared__ float csH[NCH][FF];
    __shared__ float csL[NCH][FF];
    const int bh = blockIdx.x;
    const int wv = threadIdx.x >> 6, o = threadIdx.x & 63;
    const int lane = o;

#pragma unroll
    for (int it = 0; it < 4; ++it) {
        const int c = wv * 4 + it;
        const int base = bh * NN + c * CL;
        int   myJ  = bjG[base + (lane & 31)];
        float myE1 = eHG[base + (lane & 31)];
        float myE2 = eLG[base + (lane & 31)];
        float aH = 0.f, aL = 0.f;
#pragma unroll
        for (int bt = 0; bt < 2; ++bt) {
            float vb[16];
#pragma unroll
            for (int r = 0; r < 16; ++r) {
                int j = __shfl(myJ, bt * 16 + r, 64);
                vb[r] = __bfloat162float(hpB[((size_t)bh * NN + j) * FF + o]);
            }
#pragma unroll
            for (int r = 0; r < 16; ++r) {
                float e1 = __shfl(myE1, bt * 16 + r, 64);
                float e2 = __shfl(myE2, bt * 16 + r, 64);
                aH += e1 * vb[r]; aL += e2 * vb[r];
            }
        }
        csH[c][o] = aH; csL[c][o] = aL;
    }
    __syncthreads();
    if (wv == 0) {
        float run = 0.f;
        for (int c = 0; c < NCH; ++c) {
            oHv[((size_t)bh * (NCH + 1) + c) * FF + o] = run;
            run += csH[c][o];
        }
        oHv[((size_t)bh * (NCH + 1) + NCH) * FF + o] = run;   // TH
    } else if (wv == 1) {
        float run = 0.f;
        for (int c = 0; c < NCH; ++c) {
            oLv[((size_t)bh * (NCH + 1) + c) * FF + o] = run;
            run += csL[c][o];
        }
        oLv[((size_t)bh * (NCH + 1) + NCH) * FF + o] = run;
    }
}

// ---- Kernel 4: ordered chunk sweep w/ LDS row window, emit at cut ------------
__global__ __launch_bounds__(256) void k_emit(
    const int* __restrict__ bjG, const float* __restrict__ eHG, const float* __restrict__ eLG,
    const __hip_bfloat16* __restrict__ hpB,
    const float* __restrict__ oHv, const float* __restrict__ oLv,
    const int* __restrict__ chunkRowSt, const int* __restrict__ rowIdx,
    const float* __restrict__ rowA, const float* __restrict__ rowB,
    const int* __restrict__ rowK,
    const void* __restrict__ bias, const int* __restrict__ flag, void* __restrict__ out)
{
    __shared__ int   wK[4][64];
    __shared__ int   wI[4][64];
    __shared__ float wA[4][64];
    __shared__ float wB[4][64];

    const int b16 = flag[0];
    const int wv = threadIdx.x >> 6, o = threadIdx.x & 63;
    const int lane = o;
    const int cid = blockIdx.x * 4 + wv;
    const int bh = cid >> 6, c = cid & (NCH - 1);

    float runH = oHv[((size_t)bh * (NCH + 1) + c) * FF + o];
    float runL = oLv[((size_t)bh * (NCH + 1) + c) * FF + o];
    const float TH = oHv[((size_t)bh * (NCH + 1) + NCH) * FF + o];
    const float biasv = LDIN(bias, o, b16);

    int pos = chunkRowSt[bh * (NCH + 1) + c];
    const int en = chunkRowSt[bh * (NCH + 1) + c + 1];
    int wbase = pos, wcount = 0;
    {
        int n = en - wbase; if (n > 64) n = 64;
        wcount = n;
        if (lane < n) {
            int g = bh * NN + wbase + lane;
            wK[wv][lane] = rowK[g]; wI[wv][lane] = rowIdx[g];
            wA[wv][lane] = rowA[g]; wB[wv][lane] = rowB[g];
        }
    }

    const int base = bh * NN + c * CL;
    int   myJ  = bjG[base + (lane & 31)];
    float myE1 = eHG[base + (lane & 31)];
    float myE2 = eLG[base + (lane & 31)];

#pragma unroll
    for (int bt = 0; bt < 2; ++bt) {
        float vb[16];
#pragma unroll
        for (int r = 0; r < 16; ++r) {
            int j = __shfl(myJ, bt * 16 + r, 64);
            vb[r] = __bfloat162float(hpB[((size_t)bh * NN + j) * FF + o]);
        }
#pragma unroll
        for (int r = 0; r < 16; ++r) {
            const int km = c * CL + bt * 16 + r;
            while (pos < en) {
                if (pos - wbase >= wcount) {          // refill window
                    wbase = pos;
                    int n = en - wbase; if (n > 64) n = 64;
                    wcount = n;
                    if (lane < n) {
                        int g = bh * NN + wbase + lane;
                        wK[wv][lane] = rowK[g]; wI[wv][lane] = rowIdx[g];
                        wA[wv][lane] = rowA[g]; wB[wv][lane] = rowB[g];
                    }
                }
                int wl = pos - wbase;
                if (wK[wv][wl] != km) break;
                float res = wA[wv][wl] * (TH - runH) + wB[wv][wl] * runL + biasv;
                const size_t oi = ((size_t)bh * NN + wI[wv][wl]) * FF + o;
                if (b16) ((__hip_bfloat16*)out)[oi] = __float2bfloat16(res);
                else     ((float*)out)[oi] = res;
                ++pos;
            }
            float e1 = __shfl(myE1, bt * 16 + r, 64);
            float e2 = __shfl(myE2, bt * 16 + r, 64);
            runH += e1 * vb[r];
            runL += e2 * vb[r];
        }
    }
    while (pos < en) {        // rows with k at chunk end (incl. k==NN)
        if (pos - wbase >= wcount) {
            wbase = pos;
            int n = en - wbase; if (n > 64) n = 64;
            wcount = n;
            if (lane < n) {
                int g = bh * NN + wbase + lane;
                wK[wv][lane] = rowK[g]; wI[wv][lane] = rowIdx[g];
                wA[wv][lane] = rowA[g]; wB[wv][lane] = rowB[g];
            }
        }
        int wl = pos - wbase;
        float res = wA[wv][wl] * (TH - runH) + wB[wv][wl] * runL + biasv;
        const size_t oi = ((size_t)bh * NN + wI[wv][wl]) * FF + o;
        if (b16) ((__hip_bfloat16*)out)[oi] = __float2bfloat16(res);
        else     ((float*)out)[oi] = res;
        ++pos;
    }
}

extern "C" void kernel_launch(void* const* d_in, const int* in_sizes, int n_in,
                              void* d_out, int out_size, void* d_ws, size_t ws_size,
                              hipStream_t stream) {
    const void* h    = d_in[0];
    // d_in[1] = adj (bool) — unused by reference
    const void* w    = d_in[2];
    const void* asrc = d_in[3];
    const void* adst = d_in[4];
    const void* bias = d_in[5];

    float* ws = (float*)d_ws;
    int*   flag = (int*)ws;                               // 16 ints (pad/align)
    __hip_bfloat16* hpB = (__hip_bfloat16*)(ws + 16);     // BH*NN*FF bf16
    float* sArr = ws + 16 + (size_t)BH * NN * FF / 2;     // BH*NN
    float* dArr = sArr + BH * NN;
    int*   bjG  = (int*)(dArr + BH * NN);                 // BH*NN
    float* eHG  = (float*)(bjG + BH * NN);
    float* eLG  = eHG + BH * NN;
    int*   rowIdx = (int*)(eLG + BH * NN);                // BH*NN
    float* rowA = (float*)(rowIdx + BH * NN);
    float* rowB = rowA + BH * NN;
    int*   rowK = (int*)(rowB + BH * NN);
    int*   chunkRowSt = rowK + BH * NN;                   // BH*(NCH+1)
    float* oHv  = (float*)(chunkRowSt + BH * (NCH + 1));  // BH*(NCH+1)*FF
    float* oLv  = oHv + (size_t)BH * (NCH + 1) * FF;

    k_proj<<<BDIM * NH * 32, 256, 0, stream>>>(h, w, asrc, adst, hpB, sArr, dArr, flag);
    k_bin<<<BH, 1024, 0, stream>>>(sArr, dArr, bjG, eHG, eLG,
                                   rowIdx, rowA, rowB, rowK, chunkRowSt);
    k_sum<<<BH, 1024, 0, stream>>>(bjG, eHG, eLG, hpB, oHv, oLv);
    k_emit<<<BH * NCH / 4, 256, 0, stream>>>(bjG, eHG, eLG, hpB, oHv, oLv,
                                             chunkRowSt, rowIdx, rowA, rowB, rowK,
                                             bias, flag, d_out);
}